// Round 13
// baseline (390.267 us; speedup 1.0000x reference)
//
#include <hip/hip_runtime.h>

#define NPTS 100000
#define NK   1600000   // NPTS * 16

typedef __attribute__((ext_vector_type(8))) short bf16x8;
typedef __attribute__((ext_vector_type(4))) float f32x4;
typedef union { bf16x8 v; unsigned u[4]; } fragu;

#define MFMA(a,b,c) __builtin_amdgcn_mfma_f32_16x16x32_bf16((a),(b),(c),0,0,0)

// ws layout: fragment tables, then ex = x@W01x (bf16) and y (bf16).
#define WS_W01  0
#define WS_WBIL 1536
#define WS_W2A  5632
#define WS_W2B  7680
#define WS_WPE  8704
#define WS_BYTES 21504                          // tables (shorts*2)
#define WS_EX    WS_BYTES                       // 100000*16*2 = 3,200,000 B
#define WS_YBF   (WS_BYTES + 3200000)           // 100000*64*2 = 12,800,000 B
#define WS_NEED  (WS_BYTES + 3200000 + 12800000)

__device__ inline unsigned cvtpk(float lo, float hi) {
  unsigned r;
  asm("v_cvt_pk_bf16_f32 %0, %1, %2" : "=v"(r) : "v"(lo), "v"(hi));
  return r;
}
__device__ inline short bfr(float f) {  // RNE f32->bf16
  unsigned u = __float_as_uint(f);
  u += 0x7fff + ((u >> 16) & 1);
  return (short)(u >> 16);
}
__device__ inline float bflo(unsigned u) { return __uint_as_float(u << 16); }
__device__ inline float bfhi(unsigned u) { return __uint_as_float(u & 0xffff0000u); }

template<int CTRL>
__device__ inline float fdpp(float x) {
  return __int_as_float(__builtin_amdgcn_update_dpp(
      0, __float_as_int(x), CTRL, 0xF, 0xF, true));
}
template<int XM>
__device__ inline float fswz(float x) {
  return __int_as_float(__builtin_amdgcn_ds_swizzle(
      __float_as_int(x), 0x1F | (XM << 10)));
}
__device__ inline unsigned bpermu(int src, unsigned v) {
  return (unsigned)__builtin_amdgcn_ds_bpermute(src << 2, (int)v);
}
__device__ inline float bpermf(int src, float v) {
  return __int_as_float(__builtin_amdgcn_ds_bpermute(src << 2, __float_as_int(v)));
}
__device__ inline int bpermi(int src, int v) {
  return __builtin_amdgcn_ds_bpermute(src << 2, v);
}

// ---------------------------------------------------------------------------
// Fused prologue: blocks 0..24999 compute y=x@W3+b3 (bf16) AND the per-point
// projection ex = x@W01[3:,:] (bf16, 16 chans). Block 25000 packs the weight
// fragment tables.
// ---------------------------------------------------------------------------
__global__ __launch_bounds__(256) void k_pre(
    const float* __restrict__ x, const float* __restrict__ W3,
    const float* __restrict__ b3,
    const float* __restrict__ W01, const float* __restrict__ b01,
    const float* __restrict__ Wbil,
    const float* __restrict__ W2a, const float* __restrict__ W2b,
    const float* __restrict__ Wp2, const float* __restrict__ bp2,
    short* __restrict__ ws, short* __restrict__ exbf, short* __restrict__ ybf)
{
  const int b = blockIdx.x;
  if (b < 25000) {
    int t = b * 256 + threadIdx.x;
    int i = __builtin_amdgcn_readfirstlane(t >> 6);
    int c = t & 63;
    const float* xr = x + i * 64;
    float acc = b3[c];
#pragma unroll
    for (int k = 0; k < 64; ++k)
      acc = fmaf(xr[k], W3[k * 64 + c], acc);
    ybf[i * 64 + c] = bfr(acc);
    if (c < 16) {
      float a2 = 0.f;
#pragma unroll
      for (int k = 0; k < 64; ++k)
        a2 = fmaf(xr[k], W01[(3 + k) * 16 + c], a2);
      exbf[i * 16 + c] = bfr(a2);
    }
    return;
  }
  // ---- weight-table prep (single block)
  const int t = threadIdx.x;
  for (int i = t; i < 3 * 512; i += 256) {
    int tt = i & 7, l = (i >> 3) & 63, kc = i >> 9;
    int o = l & 15, k = kc * 32 + ((l >> 4) << 3) + tt;
    float v = 0.f;
    if (k < 64) v = W01[(3 + k) * 16 + o];
    else if (k < 67) v = W01[(k - 64) * 16 + o];
    else if (k == 67) v = b01[o];
    ws[WS_W01 + i] = bfr(v);
  }
  for (int i = t; i < 8 * 512; i += 256) {
    int tt = i & 7, l = (i >> 3) & 63, kc = i >> 9;
    int o = l & 15, k = kc * 32 + ((l >> 4) << 3) + tt;
    ws[WS_WBIL + i] = bfr(Wbil[o * 256 + k]);
  }
  for (int i = t; i < 4 * 512; i += 256) {
    int tt = i & 7, l = (i >> 3) & 63, nt = i >> 9;
    int c = nt * 16 + (l & 15), k = ((l >> 4) << 3) + tt;
    ws[WS_W2A + i] = bfr(W2a[k * 64 + c]);
  }
  for (int i = t; i < 2 * 512; i += 256) {
    int tt = i & 7, l = (i >> 3) & 63, kc = i >> 9;
    int m = l & 15, k = kc * 32 + ((l >> 4) << 3) + tt;
    ws[WS_W2B + i] = bfr(m < 8 ? W2b[k * 8 + m] : 0.f);
  }
  for (int i = t; i < 4 * 512; i += 256) {
    int tt = i & 7, l = (i >> 3) & 63, nt = i >> 9;
    int c = nt * 16 + (l & 15), k = ((l >> 4) << 3) + tt;
    float v = 0.f;
    if (k < 3) v = Wp2[k * 64 + c]; else if (k == 3) v = bp2[c];
    ws[WS_WPE + i] = bfr(v);
  }
}

// ---------------------------------------------------------------------------
// Fallback-path kernels (small ws): identical to earlier rounds.
// ---------------------------------------------------------------------------
__global__ __launch_bounds__(256) void k_prep(
    const float* __restrict__ W01, const float* __restrict__ b01,
    const float* __restrict__ Wbil,
    const float* __restrict__ W2a, const float* __restrict__ W2b,
    const float* __restrict__ Wp2, const float* __restrict__ bp2,
    short* __restrict__ ws)
{
  const int t = threadIdx.x;
  for (int i = t; i < 3 * 512; i += 256) {
    int tt = i & 7, l = (i >> 3) & 63, kc = i >> 9;
    int o = l & 15, k = kc * 32 + ((l >> 4) << 3) + tt;
    float v = 0.f;
    if (k < 64) v = W01[(3 + k) * 16 + o];
    else if (k < 67) v = W01[(k - 64) * 16 + o];
    else if (k == 67) v = b01[o];
    ws[WS_W01 + i] = bfr(v);
  }
  for (int i = t; i < 8 * 512; i += 256) {
    int tt = i & 7, l = (i >> 3) & 63, kc = i >> 9;
    int o = l & 15, k = kc * 32 + ((l >> 4) << 3) + tt;
    ws[WS_WBIL + i] = bfr(Wbil[o * 256 + k]);
  }
  for (int i = t; i < 4 * 512; i += 256) {
    int tt = i & 7, l = (i >> 3) & 63, nt = i >> 9;
    int c = nt * 16 + (l & 15), k = ((l >> 4) << 3) + tt;
    ws[WS_W2A + i] = bfr(W2a[k * 64 + c]);
  }
  for (int i = t; i < 2 * 512; i += 256) {
    int tt = i & 7, l = (i >> 3) & 63, kc = i >> 9;
    int m = l & 15, k = kc * 32 + ((l >> 4) << 3) + tt;
    ws[WS_W2B + i] = bfr(m < 8 ? W2b[k * 8 + m] : 0.f);
  }
  for (int i = t; i < 4 * 512; i += 256) {
    int tt = i & 7, l = (i >> 3) & 63, nt = i >> 9;
    int c = nt * 16 + (l & 15), k = ((l >> 4) << 3) + tt;
    float v = 0.f;
    if (k < 3) v = Wp2[k * 64 + c]; else if (k == 3) v = bp2[c];
    ws[WS_WPE + i] = bfr(v);
  }
}

__global__ __launch_bounds__(256) void k_xw3f(
    const float* __restrict__ x, const float* __restrict__ W3,
    const float* __restrict__ b3, float* __restrict__ y)
{
  int t = blockIdx.x * 256 + threadIdx.x;
  int i = __builtin_amdgcn_readfirstlane(t >> 6);
  int c = t & 63;
  if (i >= NPTS) return;
  const float* xr = x + i * 64;
  float acc = b3[c];
#pragma unroll
  for (int k = 0; k < 64; ++k)
    acc = fmaf(xr[k], W3[k * 64 + c], acc);
  y[i * 64 + c] = acc;
}

// ---------------------------------------------------------------------------
// Main: register-resident transposed MFMA chain, zero __shared__.
// BF path: GEMM1 replaced by 32B ex[idx] gather + 12 scalar FMAs (the x@W01x
// projection is precomputed per point in k_pre). Rest identical to R7/R12.
// ---------------------------------------------------------------------------
template<bool BF>
__global__ __launch_bounds__(256, 5) void k_main(
    const float* __restrict__ p, const float* __restrict__ x,
    const int* __restrict__ knn, const short* __restrict__ wsf,
    const float* __restrict__ W01, const float* __restrict__ b01,
    const float* __restrict__ Wp1, const float* __restrict__ bp1,
    const float* __restrict__ bnp_s, const float* __restrict__ bnp_b,
    const float* __restrict__ bbil,
    const float* __restrict__ bn2a_s, const float* __restrict__ bn2a_b,
    const float* __restrict__ bn2b_s, const float* __restrict__ bn2b_b,
    const float* __restrict__ W2c, const float* __restrict__ b2c,
    const float* __restrict__ Wp2, const float* __restrict__ bp2,
    const void* __restrict__ yv_, const void* __restrict__ exbf_,
    float* __restrict__ x_out, float* __restrict__ x_knn,
    float* __restrict__ knn_f, float* __restrict__ p_r)   // may be null
{
  const int tid  = threadIdx.x;
  const int lane = tid & 63;
  const int mloc = lane & 15;
  const int kblk = lane >> 4;
  const int row  = blockIdx.x * 256 + tid;   // grid exact
  const int n    = row >> 4;
  const int j    = row & 15;
  const int idx  = knn[row];

  const float pr0 = p[idx * 3 + 0] - p[n * 3 + 0];
  const float pr1 = p[idx * 3 + 1] - p[n * 3 + 1];
  const float pr2 = p[idx * 3 + 2] - p[n * 3 + 2];

  float q0, q1, q2;
  {
    float v0 = bp1[0] + pr0 * Wp1[0] + pr1 * Wp1[3] + pr2 * Wp1[6];
    float v1 = bp1[1] + pr0 * Wp1[1] + pr1 * Wp1[4] + pr2 * Wp1[7];
    float v2 = bp1[2] + pr0 * Wp1[2] + pr1 * Wp1[5] + pr2 * Wp1[8];
    q0 = fmaxf(fmaf(v0, bnp_s[0], bnp_b[0]), 0.f);
    q1 = fmaxf(fmaf(v1, bnp_s[1], bnp_b[1]), 0.f);
    q2 = fmaxf(fmaf(v2, bnp_s[2], bnp_b[2]), 0.f);
  }

#define FR(off, idx_) (((const bf16x8*)wsf)[(off) / 8 + (idx_)])

  // ---- GEMM1^T: lane holds e chans kblk*4..+4 (packed bf16) of neighbor mloc
  unsigned epk[4][2];
  if constexpr (BF) {
    // ex[idx] gather (32B/row, 8B/lane) + pr @ W01[0:3] + b01, all scalar.
    f32x4 w0 = *(const f32x4*)&W01[ 0 + kblk * 4];
    f32x4 w1 = *(const f32x4*)&W01[16 + kblk * 4];
    f32x4 w2 = *(const f32x4*)&W01[32 + kblk * 4];
    f32x4 bb = *(const f32x4*)&b01[kblk * 4];
    const unsigned* ex2 = (const unsigned*)exbf_;
#pragma unroll
    for (int g = 0; g < 4; ++g) {
      const int src = g * 16 + mloc;
      int   ridx = bpermi(src, idx);
      float p0s  = bpermf(src, pr0);
      float p1s  = bpermf(src, pr1);
      float p2s  = bpermf(src, pr2);
      uint2 exw = *(const uint2*)&ex2[ridx * 8 + kblk * 2];
      float e0 = bflo(exw.x) + bb[0];
      float e1 = bfhi(exw.x) + bb[1];
      float e2 = bflo(exw.y) + bb[2];
      float e3 = bfhi(exw.y) + bb[3];
      e0 = fmaf(p0s, w0[0], e0); e0 = fmaf(p1s, w1[0], e0); e0 = fmaf(p2s, w2[0], e0);
      e1 = fmaf(p0s, w0[1], e1); e1 = fmaf(p1s, w1[1], e1); e1 = fmaf(p2s, w2[1], e1);
      e2 = fmaf(p0s, w0[2], e2); e2 = fmaf(p1s, w1[2], e2); e2 = fmaf(p2s, w2[2], e2);
      e3 = fmaf(p0s, w0[3], e3); e3 = fmaf(p1s, w1[3], e3); e3 = fmaf(p2s, w2[3], e3);
      epk[g][0] = cvtpk(fmaxf(e0, 0.f), fmaxf(e1, 0.f));
      epk[g][1] = cvtpk(fmaxf(e2, 0.f), fmaxf(e3, 0.f));
    }
  } else {
    bf16x8 bw0 = FR(WS_W01, 0 * 64 + lane);
    bf16x8 bw1 = FR(WS_W01, 1 * 64 + lane);
    bf16x8 bw2 = FR(WS_W01, 2 * 64 + lane);
    const float4* x4 = (const float4*)x;
#pragma unroll
    for (int g = 0; g < 4; ++g) {
      const int src = g * 16 + mloc;
      int   ridx = bpermi(src, idx);
      float p0s  = bpermf(src, pr0);
      float p1s  = bpermf(src, pr1);
      float p2s  = bpermf(src, pr2);
      f32x4 acc = {0.f, 0.f, 0.f, 0.f};
      {
        float4 xa = x4[ridx * 16 + kblk * 2];
        float4 xb = x4[ridx * 16 + kblk * 2 + 1];
        fragu B;
        B.u[0] = cvtpk(xa.x, xa.y); B.u[1] = cvtpk(xa.z, xa.w);
        B.u[2] = cvtpk(xb.x, xb.y); B.u[3] = cvtpk(xb.z, xb.w);
        acc = MFMA(bw0, B.v, acc);
      }
      {
        float4 xa = x4[ridx * 16 + 8 + kblk * 2];
        float4 xb = x4[ridx * 16 + 9 + kblk * 2];
        fragu B;
        B.u[0] = cvtpk(xa.x, xa.y); B.u[1] = cvtpk(xa.z, xa.w);
        B.u[2] = cvtpk(xb.x, xb.y); B.u[3] = cvtpk(xb.z, xb.w);
        acc = MFMA(bw1, B.v, acc);
      }
      {
        fragu B;
        B.u[0] = (kblk == 0) ? cvtpk(p0s, p1s) : 0u;
        B.u[1] = (kblk == 0) ? cvtpk(p2s, 1.f) : 0u;
        B.u[2] = 0u; B.u[3] = 0u;
        acc = MFMA(bw2, B.v, acc);
      }
      epk[g][0] = cvtpk(fmaxf(acc[0], 0.f), fmaxf(acc[1], 0.f));
      epk[g][1] = cvtpk(fmaxf(acc[2], 0.f), fmaxf(acc[3], 0.f));
    }
  }

  // ---- per-tile mid chain: bilinear^T, pe^T, GEMM2^T, GEMM3^T
  unsigned h2p[4][2];
#pragma unroll
  for (int g = 0; g < 4; ++g) {
    float er[16];
    {
      unsigned a0 = bpermu(mloc,      epk[g][0]);
      unsigned a1 = bpermu(mloc,      epk[g][1]);
      unsigned b0 = bpermu(mloc + 16, epk[g][0]);
      unsigned b1 = bpermu(mloc + 16, epk[g][1]);
      unsigned c0 = bpermu(mloc + 32, epk[g][0]);
      unsigned c1 = bpermu(mloc + 32, epk[g][1]);
      unsigned d0 = bpermu(mloc + 48, epk[g][0]);
      unsigned d1 = bpermu(mloc + 48, epk[g][1]);
      er[0] = bflo(a0);  er[1] = bfhi(a0);  er[2]  = bflo(a1); er[3]  = bfhi(a1);
      er[4] = bflo(b0);  er[5] = bfhi(b0);  er[6]  = bflo(b1); er[7]  = bfhi(b1);
      er[8] = bflo(c0);  er[9] = bfhi(c0);  er[10] = bflo(c1); er[11] = bfhi(c1);
      er[12] = bflo(d0); er[13] = bfhi(d0); er[14] = bflo(d1); er[15] = bfhi(d1);
    }
    const int jhsel = kblk & 1, ihsel = kblk >> 1;
    float ej[8];
#pragma unroll
    for (int t = 0; t < 8; ++t) ej[t] = jhsel ? er[8 + t] : er[t];
    f32x4 acc2;
    {
      f32x4 bb = *(const f32x4*)&bbil[kblk * 4];
      acc2 = bb;
#pragma unroll
      for (int kc = 0; kc < 8; ++kc) {
        bf16x8 wb = FR(WS_WBIL, kc * 64 + lane);
        float ei = ihsel ? er[2 * kc + 1] : er[2 * kc];
        fragu B;
        B.u[0] = cvtpk(ei * ej[0], ei * ej[1]);
        B.u[1] = cvtpk(ei * ej[2], ei * ej[3]);
        B.u[2] = cvtpk(ei * ej[4], ei * ej[5]);
        B.u[3] = cvtpk(ei * ej[6], ei * ej[7]);
        acc2 = MFMA(wb, B.v, acc2);
      }
    }
    // pe^T -> shrink
    f32x4 shq;
    {
      const int src = g * 16 + mloc;
      float q0s = bpermf(src, q0);
      float q1s = bpermf(src, q1);
      float q2s = bpermf(src, q2);
      fragu B;
      B.u[0] = (kblk == 0) ? cvtpk(q0s, q1s) : 0u;
      B.u[1] = (kblk == 0) ? cvtpk(q2s, 1.f) : 0u;
      B.u[2] = 0u; B.u[3] = 0u;
      f32x4 z = {0.f, 0.f, 0.f, 0.f};
      f32x4 s0 = MFMA(FR(WS_WPE, 0 * 64 + lane), B.v, z);
      f32x4 s1 = MFMA(FR(WS_WPE, 1 * 64 + lane), B.v, z);
      f32x4 s2 = MFMA(FR(WS_WPE, 2 * 64 + lane), B.v, z);
      f32x4 s3 = MFMA(FR(WS_WPE, 3 * 64 + lane), B.v, z);
#pragma unroll
      for (int r = 0; r < 4; ++r) shq[r] = s0[r] + s1[r] + s2[r] + s3[r];
    }
    unsigned pe2_0 = cvtpk(acc2[0], acc2[1]);
    unsigned pe2_1 = cvtpk(acc2[2], acc2[3]);
    unsigned psh_0 = cvtpk(shq[0], shq[1]);
    unsigned psh_1 = cvtpk(shq[2], shq[3]);
    fragu Bef;
    {
      const int s1l = mloc + 32 * (kblk & 1);
      const int s2l = s1l + 16;
      unsigned a0 = bpermu(s1l, pe2_0);
      unsigned a1 = bpermu(s1l, pe2_1);
      unsigned a2 = bpermu(s2l, pe2_0);
      unsigned a3 = bpermu(s2l, pe2_1);
      unsigned b0 = bpermu(s1l, psh_0);
      unsigned b1 = bpermu(s1l, psh_1);
      unsigned b2 = bpermu(s2l, psh_0);
      unsigned b3 = bpermu(s2l, psh_1);
      const bool lo2 = (kblk < 2);
      Bef.u[0] = lo2 ? a0 : b0; Bef.u[1] = lo2 ? a1 : b1;
      Bef.u[2] = lo2 ? a2 : b2; Bef.u[3] = lo2 ? a3 : b3;
    }
    unsigned pha[8];
#pragma unroll
    for (int nt = 0; nt < 4; ++nt) {
      bf16x8 wa = FR(WS_W2A, nt * 64 + lane);
      f32x4 z = {0.f, 0.f, 0.f, 0.f};
      f32x4 c = MFMA(wa, Bef.v, z);
      f32x4 sA = *(const f32x4*)&bn2a_s[nt * 16 + kblk * 4];
      f32x4 bA = *(const f32x4*)&bn2a_b[nt * 16 + kblk * 4];
      float h0 = fmaxf(fmaf(c[0], sA[0], bA[0]), 0.f);
      float h1 = fmaxf(fmaf(c[1], sA[1], bA[1]), 0.f);
      float h2 = fmaxf(fmaf(c[2], sA[2], bA[2]), 0.f);
      float h3 = fmaxf(fmaf(c[3], sA[3], bA[3]), 0.f);
      pha[nt * 2 + 0] = cvtpk(h0, h1);
      pha[nt * 2 + 1] = cvtpk(h2, h3);
    }
    {
      const int sAl = mloc + 32 * (kblk & 1);
      const int sBl = sAl + 16;
      const bool lo2 = (kblk < 2);
      fragu B0, B1;
      {
        unsigned a0 = bpermu(sAl, pha[0]), a1 = bpermu(sAl, pha[1]);
        unsigned a2 = bpermu(sBl, pha[0]), a3 = bpermu(sBl, pha[1]);
        unsigned b0 = bpermu(sAl, pha[2]), b1 = bpermu(sAl, pha[3]);
        unsigned b2 = bpermu(sBl, pha[2]), b3 = bpermu(sBl, pha[3]);
        B0.u[0] = lo2 ? a0 : b0; B0.u[1] = lo2 ? a1 : b1;
        B0.u[2] = lo2 ? a2 : b2; B0.u[3] = lo2 ? a3 : b3;
      }
      {
        unsigned a0 = bpermu(sAl, pha[4]), a1 = bpermu(sAl, pha[5]);
        unsigned a2 = bpermu(sBl, pha[4]), a3 = bpermu(sBl, pha[5]);
        unsigned b0 = bpermu(sAl, pha[6]), b1 = bpermu(sAl, pha[7]);
        unsigned b2 = bpermu(sBl, pha[6]), b3 = bpermu(sBl, pha[7]);
        B1.u[0] = lo2 ? a0 : b0; B1.u[1] = lo2 ? a1 : b1;
        B1.u[2] = lo2 ? a2 : b2; B1.u[3] = lo2 ? a3 : b3;
      }
      f32x4 acc3 = {0.f, 0.f, 0.f, 0.f};
      acc3 = MFMA(FR(WS_W2B, 0 * 64 + lane), B0.v, acc3);
      acc3 = MFMA(FR(WS_W2B, 1 * 64 + lane), B1.v, acc3);
      f32x4 s = *(const f32x4*)&bn2b_s[(kblk & 1) * 4];
      f32x4 b = *(const f32x4*)&bn2b_b[(kblk & 1) * 4];
      float v0 = fmaxf(fmaf(acc3[0], s[0], b[0]), 0.f);
      float v1 = fmaxf(fmaf(acc3[1], s[1], b[1]), 0.f);
      float v2 = fmaxf(fmaf(acc3[2], s[2], b[2]), 0.f);
      float v3 = fmaxf(fmaf(acc3[3], s[3], b[3]), 0.f);
      h2p[g][0] = cvtpk(v0, v1);
      h2p[g][1] = cvtpk(v2, v3);
    }
  }

  // ---- route h2 to own row
  unsigned hp0 = 0, hp1 = 0, hp2 = 0, hp3 = 0;
#pragma unroll
  for (int g = 0; g < 4; ++g) {
    unsigned t0 = bpermu(mloc,      h2p[g][0]);
    unsigned t1 = bpermu(mloc,      h2p[g][1]);
    unsigned t2 = bpermu(mloc + 16, h2p[g][0]);
    unsigned t3 = bpermu(mloc + 16, h2p[g][1]);
    const bool mine = (kblk == g);
    hp0 = mine ? t0 : hp0; hp1 = mine ? t1 : hp1;
    hp2 = mine ? t2 : hp2; hp3 = mine ? t3 : hp3;
  }
  float h2r[8];
  h2r[0] = bflo(hp0); h2r[1] = bfhi(hp0); h2r[2] = bflo(hp1); h2r[3] = bfhi(hp1);
  h2r[4] = bflo(hp2); h2r[5] = bfhi(hp2); h2r[6] = bflo(hp3); h2r[7] = bfhi(hp3);

  // ---- W2c + softmax over 16 neighbors (DPP allreduce)
  float h3[8];
#pragma unroll
  for (int b = 0; b < 8; ++b) h3[b] = b2c[b];
#pragma unroll
  for (int m = 0; m < 8; ++m) {
    float r = h2r[m];
#pragma unroll
    for (int b = 0; b < 8; ++b) h3[b] = fmaf(r, W2c[m * 8 + b], h3[b]);
  }
  float wv[8];
#pragma unroll
  for (int b = 0; b < 8; ++b) {
    float mx = h3[b];
    mx = fmaxf(mx, fdpp<0x128>(mx));
    mx = fmaxf(mx, fdpp<0x124>(mx));
    mx = fmaxf(mx, fdpp<0x122>(mx));
    mx = fmaxf(mx, fdpp<0x121>(mx));
    float ex = __expf(h3[b] - mx);
    float s = ex;
    s = s + fdpp<0x128>(s);
    s = s + fdpp<0x124>(s);
    s = s + fdpp<0x122>(s);
    s = s + fdpp<0x121>(s);
    wv[b] = ex * __builtin_amdgcn_rcpf(s);
  }

  // ---- phase 2
  float* xkrow = x_knn + (long long)row * 64;
  float xo[4];
#pragma unroll
  for (int h = 0; h < 2; ++h) {
    float v[32];
    if constexpr (BF) {
      const uint4* y4b = (const uint4*)yv_;
#pragma unroll
      for (int u2 = 0; u2 < 4; ++u2) {
        uint4 yw = y4b[idx * 8 + h * 4 + u2];
        unsigned wd[4] = {yw.x, yw.y, yw.z, yw.w};
#pragma unroll
        for (int half = 0; half < 2; ++half) {
          const int u = u2 * 2 + half;
          float comp[4] = {bflo(wd[half * 2]), bfhi(wd[half * 2]),
                           bflo(wd[half * 2 + 1]), bfhi(wd[half * 2 + 1])};
          f32x4 st;
#pragma unroll
          for (int cc = 0; cc < 4; ++cc) {
            const int c = h * 32 + u * 4 + cc;
            float pe = bp2[c] + q0 * Wp2[c] + q1 * Wp2[64 + c] + q2 * Wp2[128 + c];
            float val = (comp[cc] + pe) * wv[c & 7];
            v[u * 4 + cc] = val;
            st[cc] = val;
          }
          *(f32x4*)(xkrow + h * 32 + u * 4) = st;
        }
      }
    } else {
      const float4* y4 = (const float4*)yv_;
#pragma unroll
      for (int u = 0; u < 8; ++u) {
        float4 yw = y4[idx * 16 + h * 8 + u];
        float comp[4] = {yw.x, yw.y, yw.z, yw.w};
        f32x4 st;
#pragma unroll
        for (int cc = 0; cc < 4; ++cc) {
          const int c = h * 32 + u * 4 + cc;
          float pe = bp2[c] + q0 * Wp2[c] + q1 * Wp2[64 + c] + q2 * Wp2[128 + c];
          float val = (comp[cc] + pe) * wv[c & 7];
          v[u * 4 + cc] = val;
          st[cc] = val;
        }
        *(f32x4*)(xkrow + h * 32 + u * 4) = st;
      }
    }
    // reduce-scatter over the 16-lane group
    const bool b0 = (j & 1), b1 = (j & 2), b2 = (j & 4), b3 = (j & 8);
    float v1[16];
#pragma unroll
    for (int q = 0; q < 16; ++q) {
      float snd = b0 ? v[2 * q] : v[2 * q + 1];
      float rcv = fdpp<0xB1>(snd);
      v1[q] = (b0 ? v[2 * q + 1] : v[2 * q]) + rcv;
    }
    float v2[8];
#pragma unroll
    for (int r = 0; r < 8; ++r) {
      float snd = b1 ? v1[2 * r] : v1[2 * r + 1];
      float rcv = fdpp<0x4E>(snd);
      v2[r] = (b1 ? v1[2 * r + 1] : v1[2 * r]) + rcv;
    }
    float v3[4];
#pragma unroll
    for (int s = 0; s < 4; ++s) {
      float snd = b2 ? v2[2 * s] : v2[2 * s + 1];
      float rcv = fswz<4>(snd);
      v3[s] = (b2 ? v2[2 * s + 1] : v2[2 * s]) + rcv;
    }
    {
      float s0 = b3 ? v3[0] : v3[1];
      float s1 = b3 ? v3[2] : v3[3];
      float r0 = fswz<8>(s0);
      float r1 = fswz<8>(s1);
      xo[2 * h]     = (b3 ? v3[1] : v3[0]) + r0;
      xo[2 * h + 1] = (b3 ? v3[3] : v3[2]) + r1;
    }
  }
#pragma unroll
  for (int g = 0; g < 4; ++g)
    x_out[n * 64 + g * 16 + j] = xo[g];

  if (knn_f) {
    knn_f[row] = (float)idx;
    p_r[row * 3 + 0] = pr0;
    p_r[row * 3 + 1] = pr1;
    p_r[row * 3 + 2] = pr2;
  }
}

// ---------------------------------------------------------------------------
__global__ __launch_bounds__(256) void k_tail(
    const float* __restrict__ p, const int* __restrict__ knn,
    float* __restrict__ knn_f, float* __restrict__ p_r)
{
  int row = blockIdx.x * 256 + threadIdx.x;
  if (row >= NK) return;
  int n = row >> 4;
  int idx = knn[row];
  knn_f[row] = (float)idx;
  p_r[row * 3 + 0] = p[idx * 3 + 0] - p[n * 3 + 0];
  p_r[row * 3 + 1] = p[idx * 3 + 1] - p[n * 3 + 1];
  p_r[row * 3 + 2] = p[idx * 3 + 2] - p[n * 3 + 2];
}

// ---------------------------------------------------------------------------
extern "C" void kernel_launch(void* const* d_in, const int* in_sizes, int n_in,
                              void* d_out, int out_size, void* d_ws, size_t ws_size,
                              hipStream_t stream)
{
  const float* p    = (const float*)d_in[0];
  const float* x    = (const float*)d_in[1];
  const int*   knn  = (const int*)d_in[2];
  const float* W01  = (const float*)d_in[3];
  const float* b01  = (const float*)d_in[4];
  const float* Wbil = (const float*)d_in[5];
  const float* bbil = (const float*)d_in[6];
  const float* Wp1  = (const float*)d_in[7];
  const float* bp1  = (const float*)d_in[8];
  const float* bnps = (const float*)d_in[9];
  const float* bnpb = (const float*)d_in[10];
  const float* Wp2  = (const float*)d_in[11];
  const float* bp2  = (const float*)d_in[12];
  const float* W2a  = (const float*)d_in[13];
  const float* s2a  = (const float*)d_in[14];
  const float* b2a  = (const float*)d_in[15];
  const float* W2b  = (const float*)d_in[16];
  const float* s2b  = (const float*)d_in[17];
  const float* b2b  = (const float*)d_in[18];
  const float* W2c  = (const float*)d_in[19];
  const float* b2c  = (const float*)d_in[20];
  const float* W3   = (const float*)d_in[21];
  const float* b3   = (const float*)d_in[22];

  float* outF  = (float*)d_out;
  float* x_out = outF;                 // [N,64]
  float* x_knn = outF + 6400000;       // [N,16,64]
  float* knn_f = outF + 108800000;     // [N,16]
  float* p_r   = outF + 110400000;     // [N,16,3]
  short* wsf   = (short*)d_ws;

  if (ws_size >= (size_t)WS_NEED) {
    short* exbf = (short*)((char*)d_ws + WS_EX);
    short* ybf  = (short*)((char*)d_ws + WS_YBF);
    k_pre<<<25001, 256, 0, stream>>>(x, W3, b3, W01, b01, Wbil, W2a, W2b,
                                     Wp2, bp2, wsf, exbf, ybf);
    k_main<true><<<6250, 256, 0, stream>>>(p, x, knn, wsf, W01, b01,
                                           Wp1, bp1, bnps, bnpb,
                                           bbil, s2a, b2a, s2b, b2b, W2c, b2c,
                                           Wp2, bp2, ybf, exbf, x_out, x_knn,
                                           knn_f, p_r);
  } else {
    float* y = knn_f;                  // reuse tail for x@W3+b3 (f32)
    k_prep<<<1, 256, 0, stream>>>(W01, b01, Wbil, W2a, W2b, Wp2, bp2, wsf);
    k_xw3f<<<25000, 256, 0, stream>>>(x, W3, b3, y);
    k_main<false><<<6250, 256, 0, stream>>>(p, x, knn, wsf, W01, b01,
                                            Wp1, bp1, bnps, bnpb,
                                            bbil, s2a, b2a, s2b, b2b, W2c, b2c,
                                            Wp2, bp2, y, nullptr, x_out, x_knn,
                                            (float*)nullptr, (float*)nullptr);
    k_tail<<<6250, 256, 0, stream>>>(p, knn, knn_f, p_r);
  }
}

// Round 14
// 377.437 us; speedup vs baseline: 1.0340x; 1.0340x over previous
//
#include <hip/hip_runtime.h>

#define NPTS 100000
#define NK   1600000   // NPTS * 16

typedef __attribute__((ext_vector_type(8))) short bf16x8;
typedef __attribute__((ext_vector_type(4))) float f32x4;
typedef union { bf16x8 v; unsigned u[4]; } fragu;

#define MFMA(a,b,c) __builtin_amdgcn_mfma_f32_16x16x32_bf16((a),(b),(c),0,0,0)

// ws layout: fragment tables, then ex = x@W01x (bf16) and y (bf16).
#define WS_W01  0
#define WS_WBIL 1536
#define WS_W2A  5632
#define WS_W2B  7680
#define WS_WPE  8704
#define WS_BYTES 21504                          // tables (shorts*2)
#define WS_EX    WS_BYTES                       // 100000*16*2 = 3,200,000 B
#define WS_YBF   (WS_BYTES + 3200000)           // 100000*64*2 = 12,800,000 B
#define WS_NEED  (WS_BYTES + 3200000 + 12800000)

__device__ inline unsigned cvtpk(float lo, float hi) {
  unsigned r;
  asm("v_cvt_pk_bf16_f32 %0, %1, %2" : "=v"(r) : "v"(lo), "v"(hi));
  return r;
}
__device__ inline short bfr(float f) {  // RNE f32->bf16
  unsigned u = __float_as_uint(f);
  u += 0x7fff + ((u >> 16) & 1);
  return (short)(u >> 16);
}
__device__ inline float bflo(unsigned u) { return __uint_as_float(u << 16); }
__device__ inline float bfhi(unsigned u) { return __uint_as_float(u & 0xffff0000u); }

template<int CTRL>
__device__ inline float fdpp(float x) {
  return __int_as_float(__builtin_amdgcn_update_dpp(
      0, __float_as_int(x), CTRL, 0xF, 0xF, true));
}
template<int XM>
__device__ inline float fswz(float x) {
  return __int_as_float(__builtin_amdgcn_ds_swizzle(
      __float_as_int(x), 0x1F | (XM << 10)));
}
__device__ inline unsigned bpermu(int src, unsigned v) {
  return (unsigned)__builtin_amdgcn_ds_bpermute(src << 2, (int)v);
}
__device__ inline float bpermf(int src, float v) {
  return __int_as_float(__builtin_amdgcn_ds_bpermute(src << 2, __float_as_int(v)));
}
__device__ inline int bpermi(int src, int v) {
  return __builtin_amdgcn_ds_bpermute(src << 2, v);
}

// ---------------------------------------------------------------------------
// Fused prologue: blocks 0..24999 compute y=x@W3+b3 (bf16) AND the per-point
// projection ex = x@W01[3:,:] (bf16, 16 chans; wave-parallel lane-split).
// Block 25000 packs the weight fragment tables.
// ---------------------------------------------------------------------------
__global__ __launch_bounds__(256) void k_pre(
    const float* __restrict__ x, const float* __restrict__ W3,
    const float* __restrict__ b3,
    const float* __restrict__ W01, const float* __restrict__ b01,
    const float* __restrict__ Wbil,
    const float* __restrict__ W2a, const float* __restrict__ W2b,
    const float* __restrict__ Wp2, const float* __restrict__ bp2,
    short* __restrict__ ws, short* __restrict__ exbf, short* __restrict__ ybf)
{
  const int b = blockIdx.x;
  if (b < 25000) {
    int t = b * 256 + threadIdx.x;
    int i = __builtin_amdgcn_readfirstlane(t >> 6);
    int c = t & 63;
    const float* xr = x + i * 64;
    float acc = b3[c];
#pragma unroll
    for (int k = 0; k < 64; ++k)
      acc = fmaf(xr[k], W3[k * 64 + c], acc);
    ybf[i * 64 + c] = bfr(acc);
    // ex: wave-parallel. lane (kblk,mloc) sums k in [16*kblk, 16*kblk+16)
    // for channel mloc; reduce over kblk via xor16 (swizzle) + xor32 (bperm).
    {
      const int mloc = c & 15, kblk = c >> 4;
      float a2 = 0.f;
#pragma unroll
      for (int kk = 0; kk < 16; ++kk) {
        const int k = kblk * 16 + kk;
        a2 = fmaf(xr[k], W01[(3 + k) * 16 + mloc], a2);
      }
      a2 += fswz<16>(a2);
      a2 += bpermf(c ^ 32, a2);
      if (kblk == 0) exbf[i * 16 + mloc] = bfr(a2);
    }
    return;
  }
  // ---- weight-table prep (single block)
  const int t = threadIdx.x;
  for (int i = t; i < 3 * 512; i += 256) {
    int tt = i & 7, l = (i >> 3) & 63, kc = i >> 9;
    int o = l & 15, k = kc * 32 + ((l >> 4) << 3) + tt;
    float v = 0.f;
    if (k < 64) v = W01[(3 + k) * 16 + o];
    else if (k < 67) v = W01[(k - 64) * 16 + o];
    else if (k == 67) v = b01[o];
    ws[WS_W01 + i] = bfr(v);
  }
  for (int i = t; i < 8 * 512; i += 256) {
    int tt = i & 7, l = (i >> 3) & 63, kc = i >> 9;
    int o = l & 15, k = kc * 32 + ((l >> 4) << 3) + tt;
    ws[WS_WBIL + i] = bfr(Wbil[o * 256 + k]);
  }
  for (int i = t; i < 4 * 512; i += 256) {
    int tt = i & 7, l = (i >> 3) & 63, nt = i >> 9;
    int c = nt * 16 + (l & 15), k = ((l >> 4) << 3) + tt;
    ws[WS_W2A + i] = bfr(W2a[k * 64 + c]);
  }
  for (int i = t; i < 2 * 512; i += 256) {
    int tt = i & 7, l = (i >> 3) & 63, kc = i >> 9;
    int m = l & 15, k = kc * 32 + ((l >> 4) << 3) + tt;
    ws[WS_W2B + i] = bfr(m < 8 ? W2b[k * 8 + m] : 0.f);
  }
  for (int i = t; i < 4 * 512; i += 256) {
    int tt = i & 7, l = (i >> 3) & 63, nt = i >> 9;
    int c = nt * 16 + (l & 15), k = ((l >> 4) << 3) + tt;
    float v = 0.f;
    if (k < 3) v = Wp2[k * 64 + c]; else if (k == 3) v = bp2[c];
    ws[WS_WPE + i] = bfr(v);
  }
}

// ---------------------------------------------------------------------------
// Fallback-path kernels (small ws).
// ---------------------------------------------------------------------------
__global__ __launch_bounds__(256) void k_prep(
    const float* __restrict__ W01, const float* __restrict__ b01,
    const float* __restrict__ Wbil,
    const float* __restrict__ W2a, const float* __restrict__ W2b,
    const float* __restrict__ Wp2, const float* __restrict__ bp2,
    short* __restrict__ ws)
{
  const int t = threadIdx.x;
  for (int i = t; i < 3 * 512; i += 256) {
    int tt = i & 7, l = (i >> 3) & 63, kc = i >> 9;
    int o = l & 15, k = kc * 32 + ((l >> 4) << 3) + tt;
    float v = 0.f;
    if (k < 64) v = W01[(3 + k) * 16 + o];
    else if (k < 67) v = W01[(k - 64) * 16 + o];
    else if (k == 67) v = b01[o];
    ws[WS_W01 + i] = bfr(v);
  }
  for (int i = t; i < 8 * 512; i += 256) {
    int tt = i & 7, l = (i >> 3) & 63, kc = i >> 9;
    int o = l & 15, k = kc * 32 + ((l >> 4) << 3) + tt;
    ws[WS_WBIL + i] = bfr(Wbil[o * 256 + k]);
  }
  for (int i = t; i < 4 * 512; i += 256) {
    int tt = i & 7, l = (i >> 3) & 63, nt = i >> 9;
    int c = nt * 16 + (l & 15), k = ((l >> 4) << 3) + tt;
    ws[WS_W2A + i] = bfr(W2a[k * 64 + c]);
  }
  for (int i = t; i < 2 * 512; i += 256) {
    int tt = i & 7, l = (i >> 3) & 63, kc = i >> 9;
    int m = l & 15, k = kc * 32 + ((l >> 4) << 3) + tt;
    ws[WS_W2B + i] = bfr(m < 8 ? W2b[k * 8 + m] : 0.f);
  }
  for (int i = t; i < 4 * 512; i += 256) {
    int tt = i & 7, l = (i >> 3) & 63, nt = i >> 9;
    int c = nt * 16 + (l & 15), k = ((l >> 4) << 3) + tt;
    float v = 0.f;
    if (k < 3) v = Wp2[k * 64 + c]; else if (k == 3) v = bp2[c];
    ws[WS_WPE + i] = bfr(v);
  }
}

__global__ __launch_bounds__(256) void k_xw3f(
    const float* __restrict__ x, const float* __restrict__ W3,
    const float* __restrict__ b3, float* __restrict__ y)
{
  int t = blockIdx.x * 256 + threadIdx.x;
  int i = __builtin_amdgcn_readfirstlane(t >> 6);
  int c = t & 63;
  if (i >= NPTS) return;
  const float* xr = x + i * 64;
  float acc = b3[c];
#pragma unroll
  for (int k = 0; k < 64; ++k)
    acc = fmaf(xr[k], W3[k * 64 + c], acc);
  y[i * 64 + c] = acc;
}

// ---------------------------------------------------------------------------
// Main: register-resident transposed MFMA chain, zero __shared__.
// BF path: GEMM1 replaced by 32B ex[idx] gather + 12 scalar FMAs. Identical
// to R13's champion k_main (302 us).
// ---------------------------------------------------------------------------
template<bool BF>
__global__ __launch_bounds__(256, 5) void k_main(
    const float* __restrict__ p, const float* __restrict__ x,
    const int* __restrict__ knn, const short* __restrict__ wsf,
    const float* __restrict__ W01, const float* __restrict__ b01,
    const float* __restrict__ Wp1, const float* __restrict__ bp1,
    const float* __restrict__ bnp_s, const float* __restrict__ bnp_b,
    const float* __restrict__ bbil,
    const float* __restrict__ bn2a_s, const float* __restrict__ bn2a_b,
    const float* __restrict__ bn2b_s, const float* __restrict__ bn2b_b,
    const float* __restrict__ W2c, const float* __restrict__ b2c,
    const float* __restrict__ Wp2, const float* __restrict__ bp2,
    const void* __restrict__ yv_, const void* __restrict__ exbf_,
    float* __restrict__ x_out, float* __restrict__ x_knn,
    float* __restrict__ knn_f, float* __restrict__ p_r)   // may be null
{
  const int tid  = threadIdx.x;
  const int lane = tid & 63;
  const int mloc = lane & 15;
  const int kblk = lane >> 4;
  const int row  = blockIdx.x * 256 + tid;   // grid exact
  const int n    = row >> 4;
  const int j    = row & 15;
  const int idx  = knn[row];

  const float pr0 = p[idx * 3 + 0] - p[n * 3 + 0];
  const float pr1 = p[idx * 3 + 1] - p[n * 3 + 1];
  const float pr2 = p[idx * 3 + 2] - p[n * 3 + 2];

  float q0, q1, q2;
  {
    float v0 = bp1[0] + pr0 * Wp1[0] + pr1 * Wp1[3] + pr2 * Wp1[6];
    float v1 = bp1[1] + pr0 * Wp1[1] + pr1 * Wp1[4] + pr2 * Wp1[7];
    float v2 = bp1[2] + pr0 * Wp1[2] + pr1 * Wp1[5] + pr2 * Wp1[8];
    q0 = fmaxf(fmaf(v0, bnp_s[0], bnp_b[0]), 0.f);
    q1 = fmaxf(fmaf(v1, bnp_s[1], bnp_b[1]), 0.f);
    q2 = fmaxf(fmaf(v2, bnp_s[2], bnp_b[2]), 0.f);
  }

#define FR(off, idx_) (((const bf16x8*)wsf)[(off) / 8 + (idx_)])

  // ---- GEMM1^T: lane holds e chans kblk*4..+4 (packed bf16) of neighbor mloc
  unsigned epk[4][2];
  if constexpr (BF) {
    f32x4 w0 = *(const f32x4*)&W01[ 0 + kblk * 4];
    f32x4 w1 = *(const f32x4*)&W01[16 + kblk * 4];
    f32x4 w2 = *(const f32x4*)&W01[32 + kblk * 4];
    f32x4 bb = *(const f32x4*)&b01[kblk * 4];
    const unsigned* ex2 = (const unsigned*)exbf_;
#pragma unroll
    for (int g = 0; g < 4; ++g) {
      const int src = g * 16 + mloc;
      int   ridx = bpermi(src, idx);
      float p0s  = bpermf(src, pr0);
      float p1s  = bpermf(src, pr1);
      float p2s  = bpermf(src, pr2);
      uint2 exw = *(const uint2*)&ex2[ridx * 8 + kblk * 2];
      float e0 = bflo(exw.x) + bb[0];
      float e1 = bfhi(exw.x) + bb[1];
      float e2 = bflo(exw.y) + bb[2];
      float e3 = bfhi(exw.y) + bb[3];
      e0 = fmaf(p0s, w0[0], e0); e0 = fmaf(p1s, w1[0], e0); e0 = fmaf(p2s, w2[0], e0);
      e1 = fmaf(p0s, w0[1], e1); e1 = fmaf(p1s, w1[1], e1); e1 = fmaf(p2s, w2[1], e1);
      e2 = fmaf(p0s, w0[2], e2); e2 = fmaf(p1s, w1[2], e2); e2 = fmaf(p2s, w2[2], e2);
      e3 = fmaf(p0s, w0[3], e3); e3 = fmaf(p1s, w1[3], e3); e3 = fmaf(p2s, w2[3], e3);
      epk[g][0] = cvtpk(fmaxf(e0, 0.f), fmaxf(e1, 0.f));
      epk[g][1] = cvtpk(fmaxf(e2, 0.f), fmaxf(e3, 0.f));
    }
  } else {
    bf16x8 bw0 = FR(WS_W01, 0 * 64 + lane);
    bf16x8 bw1 = FR(WS_W01, 1 * 64 + lane);
    bf16x8 bw2 = FR(WS_W01, 2 * 64 + lane);
    const float4* x4 = (const float4*)x;
#pragma unroll
    for (int g = 0; g < 4; ++g) {
      const int src = g * 16 + mloc;
      int   ridx = bpermi(src, idx);
      float p0s  = bpermf(src, pr0);
      float p1s  = bpermf(src, pr1);
      float p2s  = bpermf(src, pr2);
      f32x4 acc = {0.f, 0.f, 0.f, 0.f};
      {
        float4 xa = x4[ridx * 16 + kblk * 2];
        float4 xb = x4[ridx * 16 + kblk * 2 + 1];
        fragu B;
        B.u[0] = cvtpk(xa.x, xa.y); B.u[1] = cvtpk(xa.z, xa.w);
        B.u[2] = cvtpk(xb.x, xb.y); B.u[3] = cvtpk(xb.z, xb.w);
        acc = MFMA(bw0, B.v, acc);
      }
      {
        float4 xa = x4[ridx * 16 + 8 + kblk * 2];
        float4 xb = x4[ridx * 16 + 9 + kblk * 2];
        fragu B;
        B.u[0] = cvtpk(xa.x, xa.y); B.u[1] = cvtpk(xa.z, xa.w);
        B.u[2] = cvtpk(xb.x, xb.y); B.u[3] = cvtpk(xb.z, xb.w);
        acc = MFMA(bw1, B.v, acc);
      }
      {
        fragu B;
        B.u[0] = (kblk == 0) ? cvtpk(p0s, p1s) : 0u;
        B.u[1] = (kblk == 0) ? cvtpk(p2s, 1.f) : 0u;
        B.u[2] = 0u; B.u[3] = 0u;
        acc = MFMA(bw2, B.v, acc);
      }
      epk[g][0] = cvtpk(fmaxf(acc[0], 0.f), fmaxf(acc[1], 0.f));
      epk[g][1] = cvtpk(fmaxf(acc[2], 0.f), fmaxf(acc[3], 0.f));
    }
  }

  // ---- per-tile mid chain: bilinear^T, pe^T, GEMM2^T, GEMM3^T
  unsigned h2p[4][2];
#pragma unroll
  for (int g = 0; g < 4; ++g) {
    float er[16];
    {
      unsigned a0 = bpermu(mloc,      epk[g][0]);
      unsigned a1 = bpermu(mloc,      epk[g][1]);
      unsigned b0 = bpermu(mloc + 16, epk[g][0]);
      unsigned b1 = bpermu(mloc + 16, epk[g][1]);
      unsigned c0 = bpermu(mloc + 32, epk[g][0]);
      unsigned c1 = bpermu(mloc + 32, epk[g][1]);
      unsigned d0 = bpermu(mloc + 48, epk[g][0]);
      unsigned d1 = bpermu(mloc + 48, epk[g][1]);
      er[0] = bflo(a0);  er[1] = bfhi(a0);  er[2]  = bflo(a1); er[3]  = bfhi(a1);
      er[4] = bflo(b0);  er[5] = bfhi(b0);  er[6]  = bflo(b1); er[7]  = bfhi(b1);
      er[8] = bflo(c0);  er[9] = bfhi(c0);  er[10] = bflo(c1); er[11] = bfhi(c1);
      er[12] = bflo(d0); er[13] = bfhi(d0); er[14] = bflo(d1); er[15] = bfhi(d1);
    }
    const int jhsel = kblk & 1, ihsel = kblk >> 1;
    float ej[8];
#pragma unroll
    for (int t = 0; t < 8; ++t) ej[t] = jhsel ? er[8 + t] : er[t];
    f32x4 acc2;
    {
      f32x4 bb = *(const f32x4*)&bbil[kblk * 4];
      acc2 = bb;
#pragma unroll
      for (int kc = 0; kc < 8; ++kc) {
        bf16x8 wb = FR(WS_WBIL, kc * 64 + lane);
        float ei = ihsel ? er[2 * kc + 1] : er[2 * kc];
        fragu B;
        B.u[0] = cvtpk(ei * ej[0], ei * ej[1]);
        B.u[1] = cvtpk(ei * ej[2], ei * ej[3]);
        B.u[2] = cvtpk(ei * ej[4], ei * ej[5]);
        B.u[3] = cvtpk(ei * ej[6], ei * ej[7]);
        acc2 = MFMA(wb, B.v, acc2);
      }
    }
    // pe^T -> shrink
    f32x4 shq;
    {
      const int src = g * 16 + mloc;
      float q0s = bpermf(src, q0);
      float q1s = bpermf(src, q1);
      float q2s = bpermf(src, q2);
      fragu B;
      B.u[0] = (kblk == 0) ? cvtpk(q0s, q1s) : 0u;
      B.u[1] = (kblk == 0) ? cvtpk(q2s, 1.f) : 0u;
      B.u[2] = 0u; B.u[3] = 0u;
      f32x4 z = {0.f, 0.f, 0.f, 0.f};
      f32x4 s0 = MFMA(FR(WS_WPE, 0 * 64 + lane), B.v, z);
      f32x4 s1 = MFMA(FR(WS_WPE, 1 * 64 + lane), B.v, z);
      f32x4 s2 = MFMA(FR(WS_WPE, 2 * 64 + lane), B.v, z);
      f32x4 s3 = MFMA(FR(WS_WPE, 3 * 64 + lane), B.v, z);
#pragma unroll
      for (int r = 0; r < 4; ++r) shq[r] = s0[r] + s1[r] + s2[r] + s3[r];
    }
    unsigned pe2_0 = cvtpk(acc2[0], acc2[1]);
    unsigned pe2_1 = cvtpk(acc2[2], acc2[3]);
    unsigned psh_0 = cvtpk(shq[0], shq[1]);
    unsigned psh_1 = cvtpk(shq[2], shq[3]);
    fragu Bef;
    {
      const int s1l = mloc + 32 * (kblk & 1);
      const int s2l = s1l + 16;
      unsigned a0 = bpermu(s1l, pe2_0);
      unsigned a1 = bpermu(s1l, pe2_1);
      unsigned a2 = bpermu(s2l, pe2_0);
      unsigned a3 = bpermu(s2l, pe2_1);
      unsigned b0 = bpermu(s1l, psh_0);
      unsigned b1 = bpermu(s1l, psh_1);
      unsigned b2 = bpermu(s2l, psh_0);
      unsigned b3 = bpermu(s2l, psh_1);
      const bool lo2 = (kblk < 2);
      Bef.u[0] = lo2 ? a0 : b0; Bef.u[1] = lo2 ? a1 : b1;
      Bef.u[2] = lo2 ? a2 : b2; Bef.u[3] = lo2 ? a3 : b3;
    }
    unsigned pha[8];
#pragma unroll
    for (int nt = 0; nt < 4; ++nt) {
      bf16x8 wa = FR(WS_W2A, nt * 64 + lane);
      f32x4 z = {0.f, 0.f, 0.f, 0.f};
      f32x4 c = MFMA(wa, Bef.v, z);
      f32x4 sA = *(const f32x4*)&bn2a_s[nt * 16 + kblk * 4];
      f32x4 bA = *(const f32x4*)&bn2a_b[nt * 16 + kblk * 4];
      float h0 = fmaxf(fmaf(c[0], sA[0], bA[0]), 0.f);
      float h1 = fmaxf(fmaf(c[1], sA[1], bA[1]), 0.f);
      float h2 = fmaxf(fmaf(c[2], sA[2], bA[2]), 0.f);
      float h3 = fmaxf(fmaf(c[3], sA[3], bA[3]), 0.f);
      pha[nt * 2 + 0] = cvtpk(h0, h1);
      pha[nt * 2 + 1] = cvtpk(h2, h3);
    }
    {
      const int sAl = mloc + 32 * (kblk & 1);
      const int sBl = sAl + 16;
      const bool lo2 = (kblk < 2);
      fragu B0, B1;
      {
        unsigned a0 = bpermu(sAl, pha[0]), a1 = bpermu(sAl, pha[1]);
        unsigned a2 = bpermu(sBl, pha[0]), a3 = bpermu(sBl, pha[1]);
        unsigned b0 = bpermu(sAl, pha[2]), b1 = bpermu(sAl, pha[3]);
        unsigned b2 = bpermu(sBl, pha[2]), b3 = bpermu(sBl, pha[3]);
        B0.u[0] = lo2 ? a0 : b0; B0.u[1] = lo2 ? a1 : b1;
        B0.u[2] = lo2 ? a2 : b2; B0.u[3] = lo2 ? a3 : b3;
      }
      {
        unsigned a0 = bpermu(sAl, pha[4]), a1 = bpermu(sAl, pha[5]);
        unsigned a2 = bpermu(sBl, pha[4]), a3 = bpermu(sBl, pha[5]);
        unsigned b0 = bpermu(sAl, pha[6]), b1 = bpermu(sAl, pha[7]);
        unsigned b2 = bpermu(sBl, pha[6]), b3 = bpermu(sBl, pha[7]);
        B1.u[0] = lo2 ? a0 : b0; B1.u[1] = lo2 ? a1 : b1;
        B1.u[2] = lo2 ? a2 : b2; B1.u[3] = lo2 ? a3 : b3;
      }
      f32x4 acc3 = {0.f, 0.f, 0.f, 0.f};
      acc3 = MFMA(FR(WS_W2B, 0 * 64 + lane), B0.v, acc3);
      acc3 = MFMA(FR(WS_W2B, 1 * 64 + lane), B1.v, acc3);
      f32x4 s = *(const f32x4*)&bn2b_s[(kblk & 1) * 4];
      f32x4 b = *(const f32x4*)&bn2b_b[(kblk & 1) * 4];
      float v0 = fmaxf(fmaf(acc3[0], s[0], b[0]), 0.f);
      float v1 = fmaxf(fmaf(acc3[1], s[1], b[1]), 0.f);
      float v2 = fmaxf(fmaf(acc3[2], s[2], b[2]), 0.f);
      float v3 = fmaxf(fmaf(acc3[3], s[3], b[3]), 0.f);
      h2p[g][0] = cvtpk(v0, v1);
      h2p[g][1] = cvtpk(v2, v3);
    }
  }

  // ---- route h2 to own row
  unsigned hp0 = 0, hp1 = 0, hp2 = 0, hp3 = 0;
#pragma unroll
  for (int g = 0; g < 4; ++g) {
    unsigned t0 = bpermu(mloc,      h2p[g][0]);
    unsigned t1 = bpermu(mloc,      h2p[g][1]);
    unsigned t2 = bpermu(mloc + 16, h2p[g][0]);
    unsigned t3 = bpermu(mloc + 16, h2p[g][1]);
    const bool mine = (kblk == g);
    hp0 = mine ? t0 : hp0; hp1 = mine ? t1 : hp1;
    hp2 = mine ? t2 : hp2; hp3 = mine ? t3 : hp3;
  }
  float h2r[8];
  h2r[0] = bflo(hp0); h2r[1] = bfhi(hp0); h2r[2] = bflo(hp1); h2r[3] = bfhi(hp1);
  h2r[4] = bflo(hp2); h2r[5] = bfhi(hp2); h2r[6] = bflo(hp3); h2r[7] = bfhi(hp3);

  // ---- W2c + softmax over 16 neighbors (DPP allreduce)
  float h3[8];
#pragma unroll
  for (int b = 0; b < 8; ++b) h3[b] = b2c[b];
#pragma unroll
  for (int m = 0; m < 8; ++m) {
    float r = h2r[m];
#pragma unroll
    for (int b = 0; b < 8; ++b) h3[b] = fmaf(r, W2c[m * 8 + b], h3[b]);
  }
  float wv[8];
#pragma unroll
  for (int b = 0; b < 8; ++b) {
    float mx = h3[b];
    mx = fmaxf(mx, fdpp<0x128>(mx));
    mx = fmaxf(mx, fdpp<0x124>(mx));
    mx = fmaxf(mx, fdpp<0x122>(mx));
    mx = fmaxf(mx, fdpp<0x121>(mx));
    float ex = __expf(h3[b] - mx);
    float s = ex;
    s = s + fdpp<0x128>(s);
    s = s + fdpp<0x124>(s);
    s = s + fdpp<0x122>(s);
    s = s + fdpp<0x121>(s);
    wv[b] = ex * __builtin_amdgcn_rcpf(s);
  }

  // ---- phase 2
  float* xkrow = x_knn + (long long)row * 64;
  float xo[4];
#pragma unroll
  for (int h = 0; h < 2; ++h) {
    float v[32];
    if constexpr (BF) {
      const uint4* y4b = (const uint4*)yv_;
#pragma unroll
      for (int u2 = 0; u2 < 4; ++u2) {
        uint4 yw = y4b[idx * 8 + h * 4 + u2];
        unsigned wd[4] = {yw.x, yw.y, yw.z, yw.w};
#pragma unroll
        for (int half = 0; half < 2; ++half) {
          const int u = u2 * 2 + half;
          float comp[4] = {bflo(wd[half * 2]), bfhi(wd[half * 2]),
                           bflo(wd[half * 2 + 1]), bfhi(wd[half * 2 + 1])};
          f32x4 st;
#pragma unroll
          for (int cc = 0; cc < 4; ++cc) {
            const int c = h * 32 + u * 4 + cc;
            float pe = bp2[c] + q0 * Wp2[c] + q1 * Wp2[64 + c] + q2 * Wp2[128 + c];
            float val = (comp[cc] + pe) * wv[c & 7];
            v[u * 4 + cc] = val;
            st[cc] = val;
          }
          *(f32x4*)(xkrow + h * 32 + u * 4) = st;
        }
      }
    } else {
      const float4* y4 = (const float4*)yv_;
#pragma unroll
      for (int u = 0; u < 8; ++u) {
        float4 yw = y4[idx * 16 + h * 8 + u];
        float comp[4] = {yw.x, yw.y, yw.z, yw.w};
        f32x4 st;
#pragma unroll
        for (int cc = 0; cc < 4; ++cc) {
          const int c = h * 32 + u * 4 + cc;
          float pe = bp2[c] + q0 * Wp2[c] + q1 * Wp2[64 + c] + q2 * Wp2[128 + c];
          float val = (comp[cc] + pe) * wv[c & 7];
          v[u * 4 + cc] = val;
          st[cc] = val;
        }
        *(f32x4*)(xkrow + h * 32 + u * 4) = st;
      }
    }
    // reduce-scatter over the 16-lane group
    const bool b0 = (j & 1), b1 = (j & 2), b2 = (j & 4), b3 = (j & 8);
    float v1[16];
#pragma unroll
    for (int q = 0; q < 16; ++q) {
      float snd = b0 ? v[2 * q] : v[2 * q + 1];
      float rcv = fdpp<0xB1>(snd);
      v1[q] = (b0 ? v[2 * q + 1] : v[2 * q]) + rcv;
    }
    float v2[8];
#pragma unroll
    for (int r = 0; r < 8; ++r) {
      float snd = b1 ? v1[2 * r] : v1[2 * r + 1];
      float rcv = fdpp<0x4E>(snd);
      v2[r] = (b1 ? v1[2 * r + 1] : v1[2 * r]) + rcv;
    }
    float v3[4];
#pragma unroll
    for (int s = 0; s < 4; ++s) {
      float snd = b2 ? v2[2 * s] : v2[2 * s + 1];
      float rcv = fswz<4>(snd);
      v3[s] = (b2 ? v2[2 * s + 1] : v2[2 * s]) + rcv;
    }
    {
      float s0 = b3 ? v3[0] : v3[1];
      float s1 = b3 ? v3[2] : v3[3];
      float r0 = fswz<8>(s0);
      float r1 = fswz<8>(s1);
      xo[2 * h]     = (b3 ? v3[1] : v3[0]) + r0;
      xo[2 * h + 1] = (b3 ? v3[3] : v3[2]) + r1;
    }
  }
#pragma unroll
  for (int g = 0; g < 4; ++g)
    x_out[n * 64 + g * 16 + j] = xo[g];

  if (knn_f) {
    knn_f[row] = (float)idx;
    p_r[row * 3 + 0] = pr0;
    p_r[row * 3 + 1] = pr1;
    p_r[row * 3 + 2] = pr2;
  }
}

// ---------------------------------------------------------------------------
__global__ __launch_bounds__(256) void k_tail(
    const float* __restrict__ p, const int* __restrict__ knn,
    float* __restrict__ knn_f, float* __restrict__ p_r)
{
  int row = blockIdx.x * 256 + threadIdx.x;
  if (row >= NK) return;
  int n = row >> 4;
  int idx = knn[row];
  knn_f[row] = (float)idx;
  p_r[row * 3 + 0] = p[idx * 3 + 0] - p[n * 3 + 0];
  p_r[row * 3 + 1] = p[idx * 3 + 1] - p[n * 3 + 1];
  p_r[row * 3 + 2] = p[idx * 3 + 2] - p[n * 3 + 2];
}

// ---------------------------------------------------------------------------
extern "C" void kernel_launch(void* const* d_in, const int* in_sizes, int n_in,
                              void* d_out, int out_size, void* d_ws, size_t ws_size,
                              hipStream_t stream)
{
  const float* p    = (const float*)d_in[0];
  const float* x    = (const float*)d_in[1];
  const int*   knn  = (const int*)d_in[2];
  const float* W01  = (const float*)d_in[3];
  const float* b01  = (const float*)d_in[4];
  const float* Wbil = (const float*)d_in[5];
  const float* bbil = (const float*)d_in[6];
  const float* Wp1  = (const float*)d_in[7];
  const float* bp1  = (const float*)d_in[8];
  const float* bnps = (const float*)d_in[9];
  const float* bnpb = (const float*)d_in[10];
  const float* Wp2  = (const float*)d_in[11];
  const float* bp2  = (const float*)d_in[12];
  const float* W2a  = (const float*)d_in[13];
  const float* s2a  = (const float*)d_in[14];
  const float* b2a  = (const float*)d_in[15];
  const float* W2b  = (const float*)d_in[16];
  const float* s2b  = (const float*)d_in[17];
  const float* b2b  = (const float*)d_in[18];
  const float* W2c  = (const float*)d_in[19];
  const float* b2c  = (const float*)d_in[20];
  const float* W3   = (const float*)d_in[21];
  const float* b3   = (const float*)d_in[22];

  float* outF  = (float*)d_out;
  float* x_out = outF;                 // [N,64]
  float* x_knn = outF + 6400000;       // [N,16,64]
  float* knn_f = outF + 108800000;     // [N,16]
  float* p_r   = outF + 110400000;     // [N,16,3]
  short* wsf   = (short*)d_ws;

  if (ws_size >= (size_t)WS_NEED) {
    short* exbf = (short*)((char*)d_ws + WS_EX);
    short* ybf  = (short*)((char*)d_ws + WS_YBF);
    k_pre<<<25001, 256, 0, stream>>>(x, W3, b3, W01, b01, Wbil, W2a, W2b,
                                     Wp2, bp2, wsf, exbf, ybf);
    k_main<true><<<6250, 256, 0, stream>>>(p, x, knn, wsf, W01, b01,
                                           Wp1, bp1, bnps, bnpb,
                                           bbil, s2a, b2a, s2b, b2b, W2c, b2c,
                                           Wp2, bp2, ybf, exbf, x_out, x_knn,
                                           knn_f, p_r);
  } else {
    float* y = knn_f;                  // reuse tail for x@W3+b3 (f32)
    k_prep<<<1, 256, 0, stream>>>(W01, b01, Wbil, W2a, W2b, Wp2, bp2, wsf);
    k_xw3f<<<25000, 256, 0, stream>>>(x, W3, b3, y);
    k_main<false><<<6250, 256, 0, stream>>>(p, x, knn, wsf, W01, b01,
                                            Wp1, bp1, bnps, bnpb,
                                            bbil, s2a, b2a, s2b, b2b, W2c, b2c,
                                            Wp2, bp2, y, nullptr, x_out, x_knn,
                                            (float*)nullptr, (float*)nullptr);
    k_tail<<<6250, 256, 0, stream>>>(p, knn, knn_f, p_r);
  }
}

// Round 15
// 353.776 us; speedup vs baseline: 1.1031x; 1.0669x over previous
//
#include <hip/hip_runtime.h>

#define NPTS 100000
#define NK   1600000   // NPTS * 16

typedef __attribute__((ext_vector_type(8))) short bf16x8;
typedef __attribute__((ext_vector_type(4))) float f32x4;
typedef union { bf16x8 v; unsigned u[4]; } fragu;

#define MFMA(a,b,c) __builtin_amdgcn_mfma_f32_16x16x32_bf16((a),(b),(c),0,0,0)

// ws layout: fragment tables, then ex = x@W01x (bf16) and y (bf16).
#define WS_W01  0
#define WS_WBIL 1536
#define WS_W2A  5632
#define WS_W2B  7680
#define WS_WPE  8704
#define WS_BYTES 21504                          // tables (shorts*2)
#define WS_EX    WS_BYTES                       // 100000*16*2 = 3,200,000 B
#define WS_YBF   (WS_BYTES + 3200000)           // 100000*64*2 = 12,800,000 B
#define WS_NEED  (WS_BYTES + 3200000 + 12800000)

__device__ inline unsigned cvtpk(float lo, float hi) {
  unsigned r;
  asm("v_cvt_pk_bf16_f32 %0, %1, %2" : "=v"(r) : "v"(lo), "v"(hi));
  return r;
}
__device__ inline short bfr(float f) {  // RNE f32->bf16
  unsigned u = __float_as_uint(f);
  u += 0x7fff + ((u >> 16) & 1);
  return (short)(u >> 16);
}
__device__ inline float bflo(unsigned u) { return __uint_as_float(u << 16); }
__device__ inline float bfhi(unsigned u) { return __uint_as_float(u & 0xffff0000u); }

template<int CTRL>
__device__ inline float fdpp(float x) {
  return __int_as_float(__builtin_amdgcn_update_dpp(
      0, __float_as_int(x), CTRL, 0xF, 0xF, true));
}
template<int XM>
__device__ inline float fswz(float x) {
  return __int_as_float(__builtin_amdgcn_ds_swizzle(
      __float_as_int(x), 0x1F | (XM << 10)));
}
__device__ inline unsigned bpermu(int src, unsigned v) {
  return (unsigned)__builtin_amdgcn_ds_bpermute(src << 2, (int)v);
}
__device__ inline float bpermf(int src, float v) {
  return __int_as_float(__builtin_amdgcn_ds_bpermute(src << 2, __float_as_int(v)));
}
__device__ inline int bpermi(int src, int v) {
  return __builtin_amdgcn_ds_bpermute(src << 2, v);
}

// ---------------------------------------------------------------------------
// Fused prologue:
//   blocks 0..24999    : y = x@W3 + b3 (bf16), scalar-load GEMM (R12 form)
//   block 25000        : weight fragment tables
//   blocks 25001..26563: ex = x@W01[3:,:] via MFMA (16 points x 16 ch / wave)
// ---------------------------------------------------------------------------
__global__ __launch_bounds__(256) void k_pre(
    const float* __restrict__ x, const float* __restrict__ W3,
    const float* __restrict__ b3,
    const float* __restrict__ W01, const float* __restrict__ b01,
    const float* __restrict__ Wbil,
    const float* __restrict__ W2a, const float* __restrict__ W2b,
    const float* __restrict__ Wp2, const float* __restrict__ bp2,
    short* __restrict__ ws, short* __restrict__ exbf, short* __restrict__ ybf)
{
  const int b = blockIdx.x;
  if (b < 25000) {
    int t = b * 256 + threadIdx.x;
    int i = __builtin_amdgcn_readfirstlane(t >> 6);
    int c = t & 63;
    const float* xr = x + i * 64;
    float acc = b3[c];
#pragma unroll
    for (int k = 0; k < 64; ++k)
      acc = fmaf(xr[k], W3[k * 64 + c], acc);
    ybf[i * 64 + c] = bfr(acc);
    return;
  }
  if (b >= 25001) {
    // ---- ex via MFMA: wave handles 16 points, lane (mloc,kblk).
    const int lane = threadIdx.x & 63;
    const int w    = threadIdx.x >> 6;
    const int mloc = lane & 15;
    const int kblk = lane >> 4;
    const int pi   = (b - 25001) * 64 + w * 16 + mloc;
    const int pis  = (pi < NPTS) ? pi : 0;
    // A-frags of W01[3:]^T (k-enum k = kc*32 + kblk*8 + t, col = mloc)
    fragu A0, A1;
#pragma unroll
    for (int h = 0; h < 4; ++h) {
      float a0 = W01[(3 +      kblk * 8 + 2 * h    ) * 16 + mloc];
      float a1 = W01[(3 +      kblk * 8 + 2 * h + 1) * 16 + mloc];
      float a2 = W01[(3 + 32 + kblk * 8 + 2 * h    ) * 16 + mloc];
      float a3 = W01[(3 + 32 + kblk * 8 + 2 * h + 1) * 16 + mloc];
      A0.u[h] = cvtpk(a0, a1);
      A1.u[h] = cvtpk(a2, a3);
    }
    // B-frags: x row of point mloc, same k-enum
    const float4* x4 = (const float4*)x;
    fragu B0, B1;
    {
      float4 xa = x4[pis * 16 + kblk * 2];
      float4 xb = x4[pis * 16 + kblk * 2 + 1];
      B0.u[0] = cvtpk(xa.x, xa.y); B0.u[1] = cvtpk(xa.z, xa.w);
      B0.u[2] = cvtpk(xb.x, xb.y); B0.u[3] = cvtpk(xb.z, xb.w);
      float4 xc = x4[pis * 16 + 8 + kblk * 2];
      float4 xd = x4[pis * 16 + 9 + kblk * 2];
      B1.u[0] = cvtpk(xc.x, xc.y); B1.u[1] = cvtpk(xc.z, xc.w);
      B1.u[2] = cvtpk(xd.x, xd.y); B1.u[3] = cvtpk(xd.z, xd.w);
    }
    f32x4 acc = {0.f, 0.f, 0.f, 0.f};
    acc = MFMA(A0.v, B0.v, acc);
    acc = MFMA(A1.v, B1.v, acc);
    if (pi < NPTS) {
      uint2 st;
      st.x = cvtpk(acc[0], acc[1]);
      st.y = cvtpk(acc[2], acc[3]);
      *(uint2*)&((unsigned*)exbf)[pi * 8 + kblk * 2] = st;
    }
    return;
  }
  // ---- weight-table prep (single block, b == 25000)
  const int t = threadIdx.x;
  for (int i = t; i < 3 * 512; i += 256) {
    int tt = i & 7, l = (i >> 3) & 63, kc = i >> 9;
    int o = l & 15, k = kc * 32 + ((l >> 4) << 3) + tt;
    float v = 0.f;
    if (k < 64) v = W01[(3 + k) * 16 + o];
    else if (k < 67) v = W01[(k - 64) * 16 + o];
    else if (k == 67) v = b01[o];
    ws[WS_W01 + i] = bfr(v);
  }
  for (int i = t; i < 8 * 512; i += 256) {
    int tt = i & 7, l = (i >> 3) & 63, kc = i >> 9;
    int o = l & 15, k = kc * 32 + ((l >> 4) << 3) + tt;
    ws[WS_WBIL + i] = bfr(Wbil[o * 256 + k]);
  }
  for (int i = t; i < 4 * 512; i += 256) {
    int tt = i & 7, l = (i >> 3) & 63, nt = i >> 9;
    int c = nt * 16 + (l & 15), k = ((l >> 4) << 3) + tt;
    ws[WS_W2A + i] = bfr(W2a[k * 64 + c]);
  }
  for (int i = t; i < 2 * 512; i += 256) {
    int tt = i & 7, l = (i >> 3) & 63, kc = i >> 9;
    int m = l & 15, k = kc * 32 + ((l >> 4) << 3) + tt;
    ws[WS_W2B + i] = bfr(m < 8 ? W2b[k * 8 + m] : 0.f);
  }
  for (int i = t; i < 4 * 512; i += 256) {
    int tt = i & 7, l = (i >> 3) & 63, nt = i >> 9;
    int c = nt * 16 + (l & 15), k = ((l >> 4) << 3) + tt;
    float v = 0.f;
    if (k < 3) v = Wp2[k * 64 + c]; else if (k == 3) v = bp2[c];
    ws[WS_WPE + i] = bfr(v);
  }
}

// ---------------------------------------------------------------------------
// Fallback-path kernels (small ws).
// ---------------------------------------------------------------------------
__global__ __launch_bounds__(256) void k_prep(
    const float* __restrict__ W01, const float* __restrict__ b01,
    const float* __restrict__ Wbil,
    const float* __restrict__ W2a, const float* __restrict__ W2b,
    const float* __restrict__ Wp2, const float* __restrict__ bp2,
    short* __restrict__ ws)
{
  const int t = threadIdx.x;
  for (int i = t; i < 3 * 512; i += 256) {
    int tt = i & 7, l = (i >> 3) & 63, kc = i >> 9;
    int o = l & 15, k = kc * 32 + ((l >> 4) << 3) + tt;
    float v = 0.f;
    if (k < 64) v = W01[(3 + k) * 16 + o];
    else if (k < 67) v = W01[(k - 64) * 16 + o];
    else if (k == 67) v = b01[o];
    ws[WS_W01 + i] = bfr(v);
  }
  for (int i = t; i < 8 * 512; i += 256) {
    int tt = i & 7, l = (i >> 3) & 63, kc = i >> 9;
    int o = l & 15, k = kc * 32 + ((l >> 4) << 3) + tt;
    ws[WS_WBIL + i] = bfr(Wbil[o * 256 + k]);
  }
  for (int i = t; i < 4 * 512; i += 256) {
    int tt = i & 7, l = (i >> 3) & 63, nt = i >> 9;
    int c = nt * 16 + (l & 15), k = ((l >> 4) << 3) + tt;
    ws[WS_W2A + i] = bfr(W2a[k * 64 + c]);
  }
  for (int i = t; i < 2 * 512; i += 256) {
    int tt = i & 7, l = (i >> 3) & 63, kc = i >> 9;
    int m = l & 15, k = kc * 32 + ((l >> 4) << 3) + tt;
    ws[WS_W2B + i] = bfr(m < 8 ? W2b[k * 8 + m] : 0.f);
  }
  for (int i = t; i < 4 * 512; i += 256) {
    int tt = i & 7, l = (i >> 3) & 63, nt = i >> 9;
    int c = nt * 16 + (l & 15), k = ((l >> 4) << 3) + tt;
    float v = 0.f;
    if (k < 3) v = Wp2[k * 64 + c]; else if (k == 3) v = bp2[c];
    ws[WS_WPE + i] = bfr(v);
  }
}

__global__ __launch_bounds__(256) void k_xw3f(
    const float* __restrict__ x, const float* __restrict__ W3,
    const float* __restrict__ b3, float* __restrict__ y)
{
  int t = blockIdx.x * 256 + threadIdx.x;
  int i = __builtin_amdgcn_readfirstlane(t >> 6);
  int c = t & 63;
  if (i >= NPTS) return;
  const float* xr = x + i * 64;
  float acc = b3[c];
#pragma unroll
  for (int k = 0; k < 64; ++k)
    acc = fmaf(xr[k], W3[k * 64 + c], acc);
  y[i * 64 + c] = acc;
}

// ---------------------------------------------------------------------------
// Main: register-resident transposed MFMA chain, zero __shared__.
// BF path: GEMM1 replaced by 32B ex[idx] gather + 12 scalar FMAs. Identical
// to the R13/R14 champion k_main (~302 us).
// ---------------------------------------------------------------------------
template<bool BF>
__global__ __launch_bounds__(256, 5) void k_main(
    const float* __restrict__ p, const float* __restrict__ x,
    const int* __restrict__ knn, const short* __restrict__ wsf,
    const float* __restrict__ W01, const float* __restrict__ b01,
    const float* __restrict__ Wp1, const float* __restrict__ bp1,
    const float* __restrict__ bnp_s, const float* __restrict__ bnp_b,
    const float* __restrict__ bbil,
    const float* __restrict__ bn2a_s, const float* __restrict__ bn2a_b,
    const float* __restrict__ bn2b_s, const float* __restrict__ bn2b_b,
    const float* __restrict__ W2c, const float* __restrict__ b2c,
    const float* __restrict__ Wp2, const float* __restrict__ bp2,
    const void* __restrict__ yv_, const void* __restrict__ exbf_,
    float* __restrict__ x_out, float* __restrict__ x_knn,
    float* __restrict__ knn_f, float* __restrict__ p_r)   // may be null
{
  const int tid  = threadIdx.x;
  const int lane = tid & 63;
  const int mloc = lane & 15;
  const int kblk = lane >> 4;
  const int row  = blockIdx.x * 256 + tid;   // grid exact
  const int n    = row >> 4;
  const int j    = row & 15;
  const int idx  = knn[row];

  const float pr0 = p[idx * 3 + 0] - p[n * 3 + 0];
  const float pr1 = p[idx * 3 + 1] - p[n * 3 + 1];
  const float pr2 = p[idx * 3 + 2] - p[n * 3 + 2];

  float q0, q1, q2;
  {
    float v0 = bp1[0] + pr0 * Wp1[0] + pr1 * Wp1[3] + pr2 * Wp1[6];
    float v1 = bp1[1] + pr0 * Wp1[1] + pr1 * Wp1[4] + pr2 * Wp1[7];
    float v2 = bp1[2] + pr0 * Wp1[2] + pr1 * Wp1[5] + pr2 * Wp1[8];
    q0 = fmaxf(fmaf(v0, bnp_s[0], bnp_b[0]), 0.f);
    q1 = fmaxf(fmaf(v1, bnp_s[1], bnp_b[1]), 0.f);
    q2 = fmaxf(fmaf(v2, bnp_s[2], bnp_b[2]), 0.f);
  }

#define FR(off, idx_) (((const bf16x8*)wsf)[(off) / 8 + (idx_)])

  // ---- GEMM1^T: lane holds e chans kblk*4..+4 (packed bf16) of neighbor mloc
  unsigned epk[4][2];
  if constexpr (BF) {
    f32x4 w0 = *(const f32x4*)&W01[ 0 + kblk * 4];
    f32x4 w1 = *(const f32x4*)&W01[16 + kblk * 4];
    f32x4 w2 = *(const f32x4*)&W01[32 + kblk * 4];
    f32x4 bb = *(const f32x4*)&b01[kblk * 4];
    const unsigned* ex2 = (const unsigned*)exbf_;
#pragma unroll
    for (int g = 0; g < 4; ++g) {
      const int src = g * 16 + mloc;
      int   ridx = bpermi(src, idx);
      float p0s  = bpermf(src, pr0);
      float p1s  = bpermf(src, pr1);
      float p2s  = bpermf(src, pr2);
      uint2 exw = *(const uint2*)&ex2[ridx * 8 + kblk * 2];
      float e0 = bflo(exw.x) + bb[0];
      float e1 = bfhi(exw.x) + bb[1];
      float e2 = bflo(exw.y) + bb[2];
      float e3 = bfhi(exw.y) + bb[3];
      e0 = fmaf(p0s, w0[0], e0); e0 = fmaf(p1s, w1[0], e0); e0 = fmaf(p2s, w2[0], e0);
      e1 = fmaf(p0s, w0[1], e1); e1 = fmaf(p1s, w1[1], e1); e1 = fmaf(p2s, w2[1], e1);
      e2 = fmaf(p0s, w0[2], e2); e2 = fmaf(p1s, w1[2], e2); e2 = fmaf(p2s, w2[2], e2);
      e3 = fmaf(p0s, w0[3], e3); e3 = fmaf(p1s, w1[3], e3); e3 = fmaf(p2s, w2[3], e3);
      epk[g][0] = cvtpk(fmaxf(e0, 0.f), fmaxf(e1, 0.f));
      epk[g][1] = cvtpk(fmaxf(e2, 0.f), fmaxf(e3, 0.f));
    }
  } else {
    bf16x8 bw0 = FR(WS_W01, 0 * 64 + lane);
    bf16x8 bw1 = FR(WS_W01, 1 * 64 + lane);
    bf16x8 bw2 = FR(WS_W01, 2 * 64 + lane);
    const float4* x4 = (const float4*)x;
#pragma unroll
    for (int g = 0; g < 4; ++g) {
      const int src = g * 16 + mloc;
      int   ridx = bpermi(src, idx);
      float p0s  = bpermf(src, pr0);
      float p1s  = bpermf(src, pr1);
      float p2s  = bpermf(src, pr2);
      f32x4 acc = {0.f, 0.f, 0.f, 0.f};
      {
        float4 xa = x4[ridx * 16 + kblk * 2];
        float4 xb = x4[ridx * 16 + kblk * 2 + 1];
        fragu B;
        B.u[0] = cvtpk(xa.x, xa.y); B.u[1] = cvtpk(xa.z, xa.w);
        B.u[2] = cvtpk(xb.x, xb.y); B.u[3] = cvtpk(xb.z, xb.w);
        acc = MFMA(bw0, B.v, acc);
      }
      {
        float4 xa = x4[ridx * 16 + 8 + kblk * 2];
        float4 xb = x4[ridx * 16 + 9 + kblk * 2];
        fragu B;
        B.u[0] = cvtpk(xa.x, xa.y); B.u[1] = cvtpk(xa.z, xa.w);
        B.u[2] = cvtpk(xb.x, xb.y); B.u[3] = cvtpk(xb.z, xb.w);
        acc = MFMA(bw1, B.v, acc);
      }
      {
        fragu B;
        B.u[0] = (kblk == 0) ? cvtpk(p0s, p1s) : 0u;
        B.u[1] = (kblk == 0) ? cvtpk(p2s, 1.f) : 0u;
        B.u[2] = 0u; B.u[3] = 0u;
        acc = MFMA(bw2, B.v, acc);
      }
      epk[g][0] = cvtpk(fmaxf(acc[0], 0.f), fmaxf(acc[1], 0.f));
      epk[g][1] = cvtpk(fmaxf(acc[2], 0.f), fmaxf(acc[3], 0.f));
    }
  }

  // ---- per-tile mid chain: bilinear^T, pe^T, GEMM2^T, GEMM3^T
  unsigned h2p[4][2];
#pragma unroll
  for (int g = 0; g < 4; ++g) {
    float er[16];
    {
      unsigned a0 = bpermu(mloc,      epk[g][0]);
      unsigned a1 = bpermu(mloc,      epk[g][1]);
      unsigned b0 = bpermu(mloc + 16, epk[g][0]);
      unsigned b1 = bpermu(mloc + 16, epk[g][1]);
      unsigned c0 = bpermu(mloc + 32, epk[g][0]);
      unsigned c1 = bpermu(mloc + 32, epk[g][1]);
      unsigned d0 = bpermu(mloc + 48, epk[g][0]);
      unsigned d1 = bpermu(mloc + 48, epk[g][1]);
      er[0] = bflo(a0);  er[1] = bfhi(a0);  er[2]  = bflo(a1); er[3]  = bfhi(a1);
      er[4] = bflo(b0);  er[5] = bfhi(b0);  er[6]  = bflo(b1); er[7]  = bfhi(b1);
      er[8] = bflo(c0);  er[9] = bfhi(c0);  er[10] = bflo(c1); er[11] = bfhi(c1);
      er[12] = bflo(d0); er[13] = bfhi(d0); er[14] = bflo(d1); er[15] = bfhi(d1);
    }
    const int jhsel = kblk & 1, ihsel = kblk >> 1;
    float ej[8];
#pragma unroll
    for (int t = 0; t < 8; ++t) ej[t] = jhsel ? er[8 + t] : er[t];
    f32x4 acc2;
    {
      f32x4 bb = *(const f32x4*)&bbil[kblk * 4];
      acc2 = bb;
#pragma unroll
      for (int kc = 0; kc < 8; ++kc) {
        bf16x8 wb = FR(WS_WBIL, kc * 64 + lane);
        float ei = ihsel ? er[2 * kc + 1] : er[2 * kc];
        fragu B;
        B.u[0] = cvtpk(ei * ej[0], ei * ej[1]);
        B.u[1] = cvtpk(ei * ej[2], ei * ej[3]);
        B.u[2] = cvtpk(ei * ej[4], ei * ej[5]);
        B.u[3] = cvtpk(ei * ej[6], ei * ej[7]);
        acc2 = MFMA(wb, B.v, acc2);
      }
    }
    // pe^T -> shrink
    f32x4 shq;
    {
      const int src = g * 16 + mloc;
      float q0s = bpermf(src, q0);
      float q1s = bpermf(src, q1);
      float q2s = bpermf(src, q2);
      fragu B;
      B.u[0] = (kblk == 0) ? cvtpk(q0s, q1s) : 0u;
      B.u[1] = (kblk == 0) ? cvtpk(q2s, 1.f) : 0u;
      B.u[2] = 0u; B.u[3] = 0u;
      f32x4 z = {0.f, 0.f, 0.f, 0.f};
      f32x4 s0 = MFMA(FR(WS_WPE, 0 * 64 + lane), B.v, z);
      f32x4 s1 = MFMA(FR(WS_WPE, 1 * 64 + lane), B.v, z);
      f32x4 s2 = MFMA(FR(WS_WPE, 2 * 64 + lane), B.v, z);
      f32x4 s3 = MFMA(FR(WS_WPE, 3 * 64 + lane), B.v, z);
#pragma unroll
      for (int r = 0; r < 4; ++r) shq[r] = s0[r] + s1[r] + s2[r] + s3[r];
    }
    unsigned pe2_0 = cvtpk(acc2[0], acc2[1]);
    unsigned pe2_1 = cvtpk(acc2[2], acc2[3]);
    unsigned psh_0 = cvtpk(shq[0], shq[1]);
    unsigned psh_1 = cvtpk(shq[2], shq[3]);
    fragu Bef;
    {
      const int s1l = mloc + 32 * (kblk & 1);
      const int s2l = s1l + 16;
      unsigned a0 = bpermu(s1l, pe2_0);
      unsigned a1 = bpermu(s1l, pe2_1);
      unsigned a2 = bpermu(s2l, pe2_0);
      unsigned a3 = bpermu(s2l, pe2_1);
      unsigned b0 = bpermu(s1l, psh_0);
      unsigned b1 = bpermu(s1l, psh_1);
      unsigned b2 = bpermu(s2l, psh_0);
      unsigned b3 = bpermu(s2l, psh_1);
      const bool lo2 = (kblk < 2);
      Bef.u[0] = lo2 ? a0 : b0; Bef.u[1] = lo2 ? a1 : b1;
      Bef.u[2] = lo2 ? a2 : b2; Bef.u[3] = lo2 ? a3 : b3;
    }
    unsigned pha[8];
#pragma unroll
    for (int nt = 0; nt < 4; ++nt) {
      bf16x8 wa = FR(WS_W2A, nt * 64 + lane);
      f32x4 z = {0.f, 0.f, 0.f, 0.f};
      f32x4 c = MFMA(wa, Bef.v, z);
      f32x4 sA = *(const f32x4*)&bn2a_s[nt * 16 + kblk * 4];
      f32x4 bA = *(const f32x4*)&bn2a_b[nt * 16 + kblk * 4];
      float h0 = fmaxf(fmaf(c[0], sA[0], bA[0]), 0.f);
      float h1 = fmaxf(fmaf(c[1], sA[1], bA[1]), 0.f);
      float h2 = fmaxf(fmaf(c[2], sA[2], bA[2]), 0.f);
      float h3 = fmaxf(fmaf(c[3], sA[3], bA[3]), 0.f);
      pha[nt * 2 + 0] = cvtpk(h0, h1);
      pha[nt * 2 + 1] = cvtpk(h2, h3);
    }
    {
      const int sAl = mloc + 32 * (kblk & 1);
      const int sBl = sAl + 16;
      const bool lo2 = (kblk < 2);
      fragu B0, B1;
      {
        unsigned a0 = bpermu(sAl, pha[0]), a1 = bpermu(sAl, pha[1]);
        unsigned a2 = bpermu(sBl, pha[0]), a3 = bpermu(sBl, pha[1]);
        unsigned b0 = bpermu(sAl, pha[2]), b1 = bpermu(sAl, pha[3]);
        unsigned b2 = bpermu(sBl, pha[2]), b3 = bpermu(sBl, pha[3]);
        B0.u[0] = lo2 ? a0 : b0; B0.u[1] = lo2 ? a1 : b1;
        B0.u[2] = lo2 ? a2 : b2; B0.u[3] = lo2 ? a3 : b3;
      }
      {
        unsigned a0 = bpermu(sAl, pha[4]), a1 = bpermu(sAl, pha[5]);
        unsigned a2 = bpermu(sBl, pha[4]), a3 = bpermu(sBl, pha[5]);
        unsigned b0 = bpermu(sAl, pha[6]), b1 = bpermu(sAl, pha[7]);
        unsigned b2 = bpermu(sBl, pha[6]), b3 = bpermu(sBl, pha[7]);
        B1.u[0] = lo2 ? a0 : b0; B1.u[1] = lo2 ? a1 : b1;
        B1.u[2] = lo2 ? a2 : b2; B1.u[3] = lo2 ? a3 : b3;
      }
      f32x4 acc3 = {0.f, 0.f, 0.f, 0.f};
      acc3 = MFMA(FR(WS_W2B, 0 * 64 + lane), B0.v, acc3);
      acc3 = MFMA(FR(WS_W2B, 1 * 64 + lane), B1.v, acc3);
      f32x4 s = *(const f32x4*)&bn2b_s[(kblk & 1) * 4];
      f32x4 b = *(const f32x4*)&bn2b_b[(kblk & 1) * 4];
      float v0 = fmaxf(fmaf(acc3[0], s[0], b[0]), 0.f);
      float v1 = fmaxf(fmaf(acc3[1], s[1], b[1]), 0.f);
      float v2 = fmaxf(fmaf(acc3[2], s[2], b[2]), 0.f);
      float v3 = fmaxf(fmaf(acc3[3], s[3], b[3]), 0.f);
      h2p[g][0] = cvtpk(v0, v1);
      h2p[g][1] = cvtpk(v2, v3);
    }
  }

  // ---- route h2 to own row
  unsigned hp0 = 0, hp1 = 0, hp2 = 0, hp3 = 0;
#pragma unroll
  for (int g = 0; g < 4; ++g) {
    unsigned t0 = bpermu(mloc,      h2p[g][0]);
    unsigned t1 = bpermu(mloc,      h2p[g][1]);
    unsigned t2 = bpermu(mloc + 16, h2p[g][0]);
    unsigned t3 = bpermu(mloc + 16, h2p[g][1]);
    const bool mine = (kblk == g);
    hp0 = mine ? t0 : hp0; hp1 = mine ? t1 : hp1;
    hp2 = mine ? t2 : hp2; hp3 = mine ? t3 : hp3;
  }
  float h2r[8];
  h2r[0] = bflo(hp0); h2r[1] = bfhi(hp0); h2r[2] = bflo(hp1); h2r[3] = bfhi(hp1);
  h2r[4] = bflo(hp2); h2r[5] = bfhi(hp2); h2r[6] = bflo(hp3); h2r[7] = bfhi(hp3);

  // ---- W2c + softmax over 16 neighbors (DPP allreduce)
  float h3[8];
#pragma unroll
  for (int b = 0; b < 8; ++b) h3[b] = b2c[b];
#pragma unroll
  for (int m = 0; m < 8; ++m) {
    float r = h2r[m];
#pragma unroll
    for (int b = 0; b < 8; ++b) h3[b] = fmaf(r, W2c[m * 8 + b], h3[b]);
  }
  float wv[8];
#pragma unroll
  for (int b = 0; b < 8; ++b) {
    float mx = h3[b];
    mx = fmaxf(mx, fdpp<0x128>(mx));
    mx = fmaxf(mx, fdpp<0x124>(mx));
    mx = fmaxf(mx, fdpp<0x122>(mx));
    mx = fmaxf(mx, fdpp<0x121>(mx));
    float ex = __expf(h3[b] - mx);
    float s = ex;
    s = s + fdpp<0x128>(s);
    s = s + fdpp<0x124>(s);
    s = s + fdpp<0x122>(s);
    s = s + fdpp<0x121>(s);
    wv[b] = ex * __builtin_amdgcn_rcpf(s);
  }

  // ---- phase 2
  float* xkrow = x_knn + (long long)row * 64;
  float xo[4];
#pragma unroll
  for (int h = 0; h < 2; ++h) {
    float v[32];
    if constexpr (BF) {
      const uint4* y4b = (const uint4*)yv_;
#pragma unroll
      for (int u2 = 0; u2 < 4; ++u2) {
        uint4 yw = y4b[idx * 8 + h * 4 + u2];
        unsigned wd[4] = {yw.x, yw.y, yw.z, yw.w};
#pragma unroll
        for (int half = 0; half < 2; ++half) {
          const int u = u2 * 2 + half;
          float comp[4] = {bflo(wd[half * 2]), bfhi(wd[half * 2]),
                           bflo(wd[half * 2 + 1]), bfhi(wd[half * 2 + 1])};
          f32x4 st;
#pragma unroll
          for (int cc = 0; cc < 4; ++cc) {
            const int c = h * 32 + u * 4 + cc;
            float pe = bp2[c] + q0 * Wp2[c] + q1 * Wp2[64 + c] + q2 * Wp2[128 + c];
            float val = (comp[cc] + pe) * wv[c & 7];
            v[u * 4 + cc] = val;
            st[cc] = val;
          }
          *(f32x4*)(xkrow + h * 32 + u * 4) = st;
        }
      }
    } else {
      const float4* y4 = (const float4*)yv_;
#pragma unroll
      for (int u = 0; u < 8; ++u) {
        float4 yw = y4[idx * 16 + h * 8 + u];
        float comp[4] = {yw.x, yw.y, yw.z, yw.w};
        f32x4 st;
#pragma unroll
        for (int cc = 0; cc < 4; ++cc) {
          const int c = h * 32 + u * 4 + cc;
          float pe = bp2[c] + q0 * Wp2[c] + q1 * Wp2[64 + c] + q2 * Wp2[128 + c];
          float val = (comp[cc] + pe) * wv[c & 7];
          v[u * 4 + cc] = val;
          st[cc] = val;
        }
        *(f32x4*)(xkrow + h * 32 + u * 4) = st;
      }
    }
    // reduce-scatter over the 16-lane group
    const bool b0 = (j & 1), b1 = (j & 2), b2 = (j & 4), b3 = (j & 8);
    float v1[16];
#pragma unroll
    for (int q = 0; q < 16; ++q) {
      float snd = b0 ? v[2 * q] : v[2 * q + 1];
      float rcv = fdpp<0xB1>(snd);
      v1[q] = (b0 ? v[2 * q + 1] : v[2 * q]) + rcv;
    }
    float v2[8];
#pragma unroll
    for (int r = 0; r < 8; ++r) {
      float snd = b1 ? v1[2 * r] : v1[2 * r + 1];
      float rcv = fdpp<0x4E>(snd);
      v2[r] = (b1 ? v1[2 * r + 1] : v1[2 * r]) + rcv;
    }
    float v3[4];
#pragma unroll
    for (int s = 0; s < 4; ++s) {
      float snd = b2 ? v2[2 * s] : v2[2 * s + 1];
      float rcv = fswz<4>(snd);
      v3[s] = (b2 ? v2[2 * s + 1] : v2[2 * s]) + rcv;
    }
    {
      float s0 = b3 ? v3[0] : v3[1];
      float s1 = b3 ? v3[2] : v3[3];
      float r0 = fswz<8>(s0);
      float r1 = fswz<8>(s1);
      xo[2 * h]     = (b3 ? v3[1] : v3[0]) + r0;
      xo[2 * h + 1] = (b3 ? v3[3] : v3[2]) + r1;
    }
  }
#pragma unroll
  for (int g = 0; g < 4; ++g)
    x_out[n * 64 + g * 16 + j] = xo[g];

  if (knn_f) {
    knn_f[row] = (float)idx;
    p_r[row * 3 + 0] = pr0;
    p_r[row * 3 + 1] = pr1;
    p_r[row * 3 + 2] = pr2;
  }
}

// ---------------------------------------------------------------------------
__global__ __launch_bounds__(256) void k_tail(
    const float* __restrict__ p, const int* __restrict__ knn,
    float* __restrict__ knn_f, float* __restrict__ p_r)
{
  int row = blockIdx.x * 256 + threadIdx.x;
  if (row >= NK) return;
  int n = row >> 4;
  int idx = knn[row];
  knn_f[row] = (float)idx;
  p_r[row * 3 + 0] = p[idx * 3 + 0] - p[n * 3 + 0];
  p_r[row * 3 + 1] = p[idx * 3 + 1] - p[n * 3 + 1];
  p_r[row * 3 + 2] = p[idx * 3 + 2] - p[n * 3 + 2];
}

// ---------------------------------------------------------------------------
extern "C" void kernel_launch(void* const* d_in, const int* in_sizes, int n_in,
                              void* d_out, int out_size, void* d_ws, size_t ws_size,
                              hipStream_t stream)
{
  const float* p    = (const float*)d_in[0];
  const float* x    = (const float*)d_in[1];
  const int*   knn  = (const int*)d_in[2];
  const float* W01  = (const float*)d_in[3];
  const float* b01  = (const float*)d_in[4];
  const float* Wbil = (const float*)d_in[5];
  const float* bbil = (const float*)d_in[6];
  const float* Wp1  = (const float*)d_in[7];
  const float* bp1  = (const float*)d_in[8];
  const float* bnps = (const float*)d_in[9];
  const float* bnpb = (const float*)d_in[10];
  const float* Wp2  = (const float*)d_in[11];
  const float* bp2  = (const float*)d_in[12];
  const float* W2a  = (const float*)d_in[13];
  const float* s2a  = (const float*)d_in[14];
  const float* b2a  = (const float*)d_in[15];
  const float* W2b  = (const float*)d_in[16];
  const float* s2b  = (const float*)d_in[17];
  const float* b2b  = (const float*)d_in[18];
  const float* W2c  = (const float*)d_in[19];
  const float* b2c  = (const float*)d_in[20];
  const float* W3   = (const float*)d_in[21];
  const float* b3   = (const float*)d_in[22];

  float* outF  = (float*)d_out;
  float* x_out = outF;                 // [N,64]
  float* x_knn = outF + 6400000;       // [N,16,64]
  float* knn_f = outF + 108800000;     // [N,16]
  float* p_r   = outF + 110400000;     // [N,16,3]
  short* wsf   = (short*)d_ws;

  if (ws_size >= (size_t)WS_NEED) {
    short* exbf = (short*)((char*)d_ws + WS_EX);
    short* ybf  = (short*)((char*)d_ws + WS_YBF);
    // 25000 y-blocks + 1 table block + 1563 ex-MFMA blocks
    k_pre<<<26564, 256, 0, stream>>>(x, W3, b3, W01, b01, Wbil, W2a, W2b,
                                     Wp2, bp2, wsf, exbf, ybf);
    k_main<true><<<6250, 256, 0, stream>>>(p, x, knn, wsf, W01, b01,
                                           Wp1, bp1, bnps, bnpb,
                                           bbil, s2a, b2a, s2b, b2b, W2c, b2c,
                                           Wp2, bp2, ybf, exbf, x_out, x_knn,
                                           knn_f, p_r);
  } else {
    float* y = knn_f;                  // reuse tail for x@W3+b3 (f32)
    k_prep<<<1, 256, 0, stream>>>(W01, b01, Wbil, W2a, W2b, Wp2, bp2, wsf);
    k_xw3f<<<25000, 256, 0, stream>>>(x, W3, b3, y);
    k_main<false><<<6250, 256, 0, stream>>>(p, x, knn, wsf, W01, b01,
                                            Wp1, bp1, bnps, bnpb,
                                            bbil, s2a, b2a, s2b, b2b, W2c, b2c,
                                            Wp2, bp2, y, nullptr, x_out, x_knn,
                                            (float*)nullptr, (float*)nullptr);
    k_tail<<<6250, 256, 0, stream>>>(p, knn, knn_f, p_r);
  }
}